// Round 1
// baseline (813.535 us; speedup 1.0000x reference)
//
#include <hip/hip_runtime.h>
#include <hip/hip_bf16.h>

#define NSEQ 512
#define NRES 768
#define MSAC 64
#define PAIRC 128
#define NHEAD 8

typedef __attribute__((ext_vector_type(8))) short short8_t;
typedef __attribute__((ext_vector_type(4))) float f32x4;

__device__ __forceinline__ float bf2f(unsigned short u){
  return __uint_as_float(((unsigned int)u) << 16);
}
__device__ __forceinline__ unsigned short f2bf(float f){
  unsigned int x = __float_as_uint(f);
  x += 0x7fffu + ((x >> 16) & 1u);   // RTNE
  return (unsigned short)(x >> 16);
}

// ---------------- K0: mask -> additive bias per k ----------------
__global__ void k_maskbias(const float* __restrict__ mask, float* __restrict__ bias){
  int k = blockIdx.x * 256 + threadIdx.x;
  if (k >= NRES) return;
  float m = -1e30f;
  for (int b = 0; b < NSEQ; ++b) m = fmaxf(m, mask[(size_t)b * NRES + k]);
  bias[k] = 1e9f * (bf2f(f2bf(m)) - 1.0f);   // reference casts max to bf16 first
}

// ------- K1: pair LN + logits + softmax -> weights bf16 [h][q][k] -------
// block = 256 thr = 4 waves, one q per block. 8-lane groups: lane l handles
// k = base + l/8, c-range (l%8)*16. Logit weights packed bf16 in VGPR.
__global__ __launch_bounds__(256) void k_pair(
    const float* __restrict__ pair, const float* __restrict__ pscale,
    const float* __restrict__ pbias, const float* __restrict__ wl,
    const float* __restrict__ mbias, unsigned short* __restrict__ weights)
{
  __shared__ float lg[NHEAD][NRES];   // 24 KB
  const int q = blockIdx.x;
  const int tid = threadIdx.x;
  const int wv = tid >> 6, lane = tid & 63;
  const int g = lane & 7;
  const int c0 = g * 16;

  float scl[16], bsl[16];
  #pragma unroll
  for (int i = 0; i < 4; ++i){
    float4 s4 = *(const float4*)(pscale + c0 + i*4);
    float4 b4 = *(const float4*)(pbias  + c0 + i*4);
    scl[4*i+0]=s4.x; scl[4*i+1]=s4.y; scl[4*i+2]=s4.z; scl[4*i+3]=s4.w;
    bsl[4*i+0]=b4.x; bsl[4*i+1]=b4.y; bsl[4*i+2]=b4.z; bsl[4*i+3]=b4.w;
  }
  unsigned int wp[8][8];
  #pragma unroll
  for (int h = 0; h < 8; ++h){
    #pragma unroll
    for (int jj = 0; jj < 8; ++jj){
      float2 w2 = *(const float2*)(wl + h*PAIRC + c0 + jj*2);
      wp[h][jj] = (unsigned int)f2bf(w2.x) | ((unsigned int)f2bf(w2.y) << 16);
    }
  }

  for (int it = 0; it < 24; ++it){
    int k = it*32 + wv*8 + (lane >> 3);
    const float* prow = pair + ((size_t)q * NRES + k) * PAIRC + c0;
    float x[16];
    #pragma unroll
    for (int i = 0; i < 4; ++i){
      float4 v4 = *(const float4*)(prow + i*4);
      x[4*i+0]=v4.x; x[4*i+1]=v4.y; x[4*i+2]=v4.z; x[4*i+3]=v4.w;
    }
    float s = 0.f, ss = 0.f;
    #pragma unroll
    for (int i = 0; i < 16; ++i){ s += x[i]; ss += x[i]*x[i]; }
    #pragma unroll
    for (int m = 1; m < 8; m <<= 1){
      s  += __shfl_xor(s,  m, 64);
      ss += __shfl_xor(ss, m, 64);
    }
    float mu  = s * (1.f/128.f);
    float var = ss * (1.f/128.f) - mu*mu;
    float rs  = rsqrtf(var + 1e-5f);
    #pragma unroll
    for (int i = 0; i < 16; ++i) x[i] = (x[i] - mu) * rs * scl[i] + bsl[i];
    float ph[8];
    #pragma unroll
    for (int h = 0; h < 8; ++h){
      float p = 0.f;
      #pragma unroll
      for (int jj = 0; jj < 8; ++jj){
        unsigned int w = wp[h][jj];
        float wlo = __uint_as_float(w << 16);
        float whi = __uint_as_float(w & 0xffff0000u);
        p += x[2*jj] * wlo + x[2*jj+1] * whi;
      }
      ph[h] = p;
    }
    #pragma unroll
    for (int h = 0; h < 8; ++h){
      #pragma unroll
      for (int m = 1; m < 8; m <<= 1) ph[h] += __shfl_xor(ph[h], m, 64);
    }
    #pragma unroll
    for (int h = 0; h < 8; ++h) if (g == h) lg[h][k] = ph[h];
  }
  __syncthreads();
  // softmax: wave wv handles head rows wv and wv+4
  #pragma unroll
  for (int hh = 0; hh < 2; ++hh){
    int h = wv + hh*4;
    float mx = -1e30f;
    for (int kk = lane; kk < NRES; kk += 64) mx = fmaxf(mx, lg[h][kk] + mbias[kk]);
    #pragma unroll
    for (int m = 1; m < 64; m <<= 1) mx = fmaxf(mx, __shfl_xor(mx, m, 64));
    float sum = 0.f;
    for (int kk = lane; kk < NRES; kk += 64){
      float e = __expf(lg[h][kk] + mbias[kk] - mx);
      lg[h][kk] = e; sum += e;
    }
    #pragma unroll
    for (int m = 1; m < 64; m <<= 1) sum += __shfl_xor(sum, m, 64);
    float inv = 1.0f / sum;
    unsigned short* wrow = weights + ((size_t)h * NRES + q) * NRES;
    for (int kk = lane; kk < NRES; kk += 64) wrow[kk] = f2bf(lg[h][kk] * inv);
  }
}

// ------- K3: act LN + v(bf16,[h][bc][k]) + gate(bf16,[b][k][64]) -------
// block = (b, 64 k). wave per k-row; per-lane output weights in VGPR;
// v transposed through LDS so global v writes are k-contiguous.
__global__ __launch_bounds__(256) void k_act(
    const float* __restrict__ act, const float* __restrict__ ascale,
    const float* __restrict__ abias, const float* __restrict__ vproj,
    const float* __restrict__ wgate, unsigned short* __restrict__ v,
    unsigned short* __restrict__ gate)
{
  __shared__ float xsh[4][64];
  __shared__ unsigned short vsh[64][72];   // [hc][k_local], pad 72 for aligned b128
  const int b  = blockIdx.x / 12;
  const int k0 = (blockIdx.x % 12) * 64;
  const int tid = threadIdx.x, wv = tid >> 6, lane = tid & 63;

  float wvj[64], wgj[64];
  #pragma unroll
  for (int i = 0; i < 64; ++i) wvj[i] = vproj[i*64 + lane];   // v_proj[i][hc=lane]
  #pragma unroll
  for (int i4 = 0; i4 < 16; ++i4){
    float4 t = *(const float4*)(wgate + lane*64 + i4*4);      // w_gate[lane][i]
    wgj[4*i4+0]=t.x; wgj[4*i4+1]=t.y; wgj[4*i4+2]=t.z; wgj[4*i4+3]=t.w;
  }
  const float scl = ascale[lane], bsl = abias[lane];

  for (int t = 0; t < 16; ++t){
    int k = k0 + wv*16 + t;
    float x = act[((size_t)b*NRES + k)*MSAC + lane];
    float s = x, ss = x*x;
    #pragma unroll
    for (int m = 1; m < 64; m <<= 1){ s += __shfl_xor(s, m, 64); ss += __shfl_xor(ss, m, 64); }
    float mu = s*(1.f/64.f), var = ss*(1.f/64.f) - mu*mu, rs = rsqrtf(var + 1e-5f);
    float xh = (x - mu)*rs*scl + bsl;
    xsh[wv][lane] = xh;                     // wave-local broadcast buffer
    float va = 0.f, ga = 0.f;
    #pragma unroll
    for (int i = 0; i < 64; i += 4){
      float4 xx = *(const float4*)&xsh[wv][i];
      va += xx.x*wvj[i] + xx.y*wvj[i+1] + xx.z*wvj[i+2] + xx.w*wvj[i+3];
      ga += xx.x*wgj[i] + xx.y*wgj[i+1] + xx.z*wgj[i+2] + xx.w*wgj[i+3];
    }
    float gv = 1.0f / (1.0f + __expf(-ga));
    vsh[lane][wv*16 + t] = f2bf(va);
    gate[((size_t)b*NRES + k)*MSAC + lane] = f2bf(gv);
  }
  __syncthreads();
  // write v: thread t -> hc j = t/4, k-chunk = (t%4)*16 (32 B contiguous)
  const int j = tid >> 2, kc = tid & 3;
  const int h = j >> 3, c = j & 7;
  const unsigned short* src = &vsh[j][kc*16];
  uint4 d0 = *(const uint4*)(src);
  uint4 d1 = *(const uint4*)(src + 8);
  unsigned short* dst = v + ((size_t)h*4096 + (size_t)b*8 + c)*NRES + k0 + kc*16;
  *(uint4*)(dst) = d0;
  *(uint4*)(dst + 8) = d1;
}

// ------- K4: per-head GEMM  Y^T: [bc=4096] x [q=768], K=768, bf16 MFMA -------
// A = v[h] rows bc (k-major), B = weights[h] rows q (k-major). 128x128x64 tile,
// 4 waves 2x2, XOR-swizzled LDS, output written to y[q][b][hc] bf16.
__global__ __launch_bounds__(256) void k_wavg(
    const unsigned short* __restrict__ V, const unsigned short* __restrict__ W,
    unsigned short* __restrict__ Y)
{
  __shared__ unsigned char As[128*128];  // [row][128B of k], swizzled
  __shared__ unsigned char Bs[128*128];
  const int h = blockIdx.z, bx = blockIdx.x, by = blockIdx.y;
  const int tid = threadIdx.x, wid = tid >> 6, lane = tid & 63;
  const int wm = wid & 1, wn = wid >> 1;
  const unsigned short* Ag = V + (size_t)h*4096*768 + (size_t)bx*128*768;
  const unsigned short* Bg = W + (size_t)h*768*768 + (size_t)by*128*768;

  f32x4 acc[4][4];
  #pragma unroll
  for (int i=0;i<4;++i){
    #pragma unroll
    for (int jj=0;jj<4;++jj) acc[i][jj] = 0.f;
  }

  uint4 aR[4], bR[4];
  #pragma unroll
  for (int r=0;r<4;++r){
    int cid = tid + r*256, row = cid >> 3, cg = cid & 7;
    aR[r] = *(const uint4*)(Ag + (size_t)row*768 + cg*8);
    bR[r] = *(const uint4*)(Bg + (size_t)row*768 + cg*8);
  }
  for (int kt = 0; kt < 12; ++kt){
    __syncthreads();
    #pragma unroll
    for (int r=0;r<4;++r){
      int cid = tid + r*256, row = cid >> 3, cg = cid & 7;
      int off = row*128 + cg*16; off ^= (row & 7) << 4;
      *(uint4*)(As + off) = aR[r];
      *(uint4*)(Bs + off) = bR[r];
    }
    __syncthreads();
    if (kt < 11){
      #pragma unroll
      for (int r=0;r<4;++r){
        int cid = tid + r*256, row = cid >> 3, cg = cid & 7;
        aR[r] = *(const uint4*)(Ag + (size_t)row*768 + (kt+1)*64 + cg*8);
        bR[r] = *(const uint4*)(Bg + (size_t)row*768 + (kt+1)*64 + cg*8);
      }
    }
    #pragma unroll
    for (int kf = 0; kf < 2; ++kf){
      short8_t af[4], bf[4];
      const int kb = kf*64 + ((lane >> 4) << 4);   // byte offset of lane's k in row
      #pragma unroll
      for (int mf = 0; mf < 4; ++mf){
        int row = wm*64 + mf*16 + (lane & 15);
        int off = row*128 + kb; off ^= (row & 7) << 4;
        af[mf] = *(const short8_t*)(As + off);
      }
      #pragma unroll
      for (int nf = 0; nf < 4; ++nf){
        int row = wn*64 + nf*16 + (lane & 15);
        int off = row*128 + kb; off ^= (row & 7) << 4;
        bf[nf] = *(const short8_t*)(Bs + off);
      }
      #pragma unroll
      for (int mf = 0; mf < 4; ++mf){
        #pragma unroll
        for (int nf = 0; nf < 4; ++nf)
          acc[mf][nf] = __builtin_amdgcn_mfma_f32_16x16x32_bf16(af[mf], bf[nf], acc[mf][nf], 0, 0, 0);
      }
    }
  }
  // epilogue: D row = bc (lane>>4)*4+reg, col = q (lane&15); pack 4 bf16 -> 8B
  const int q0  = by*128 + wn*64 + (lane & 15);
  const int bc0 = bx*128 + wm*64 + ((lane >> 4) << 2);
  #pragma unroll
  for (int mf = 0; mf < 4; ++mf){
    int bc = bc0 + mf*16;
    size_t obase = (size_t)(bc >> 3)*64 + (size_t)h*8 + (bc & 7);
    #pragma unroll
    for (int nf = 0; nf < 4; ++nf){
      int q = q0 + nf*16;
      f32x4 a = acc[mf][nf];
      ushort4 o;
      o.x = f2bf(a[0]); o.y = f2bf(a[1]); o.z = f2bf(a[2]); o.w = f2bf(a[3]);
      *(ushort4*)(Y + (size_t)q*32768 + obase) = o;
    }
  }
}

// ------- K5: out[b][q][j] = sum_i (y*gate)[i] * w_out[j][i] -------
__global__ __launch_bounds__(256) void k_final(
    const unsigned short* __restrict__ Y, const unsigned short* __restrict__ gate,
    const float* __restrict__ wout, float* __restrict__ out)
{
  __shared__ float wsh[64*68];   // padded to break bank conflicts
  __shared__ float tsh[4][64];
  const int tid = threadIdx.x, wv = tid >> 6, lane = tid & 63;
  for (int i = tid; i < 4096; i += 256) wsh[(i >> 6)*68 + (i & 63)] = wout[i];
  __syncthreads();
  float wr[64];
  #pragma unroll
  for (int i = 0; i < 64; i += 4){
    float4 t = *(const float4*)&wsh[lane*68 + i];
    wr[i]=t.x; wr[i+1]=t.y; wr[i+2]=t.z; wr[i+3]=t.w;
  }
  const int b  = blockIdx.x / 12;
  const int q0 = (blockIdx.x % 12) * 64;
  for (int rr = 0; rr < 16; ++rr){
    int q = q0 + wv*16 + rr;
    float yv = bf2f(Y[((size_t)q*512 + b)*64 + lane]);
    float gv = bf2f(gate[((size_t)b*NRES + q)*64 + lane]);
    tsh[wv][lane] = yv * gv;
    float a = 0.f;
    #pragma unroll
    for (int i = 0; i < 64; i += 4){
      float4 tt = *(const float4*)&tsh[wv][i];
      a += tt.x*wr[i] + tt.y*wr[i+1] + tt.z*wr[i+2] + tt.w*wr[i+3];
    }
    out[((size_t)b*NRES + q)*64 + lane] = a;
  }
}

extern "C" void kernel_launch(void* const* d_in, const int* in_sizes, int n_in,
                              void* d_out, int out_size, void* d_ws, size_t ws_size,
                              hipStream_t stream) {
  (void)in_sizes; (void)n_in; (void)out_size; (void)ws_size;
  const float* act    = (const float*)d_in[0];
  const float* mask   = (const float*)d_in[1];
  const float* pair   = (const float*)d_in[2];
  const float* ascale = (const float*)d_in[3];
  const float* abias  = (const float*)d_in[4];
  const float* pscale = (const float*)d_in[5];
  const float* pbias  = (const float*)d_in[6];
  const float* wl     = (const float*)d_in[7];
  const float* vproj  = (const float*)d_in[8];
  const float* wgate  = (const float*)d_in[9];
  const float* wout   = (const float*)d_in[10];
  float* out = (float*)d_out;

  char* ws = (char*)d_ws;
  float*          mbias   = (float*)(ws);                                  // 3 KB
  unsigned short* weights = (unsigned short*)(ws + 4096);                  // 9.4 MB  [h][q][k]
  unsigned short* v       = (unsigned short*)(ws + 4096 + 9437184);        // 50.3 MB [h][bc][k]
  unsigned short* gate    = (unsigned short*)(ws + 4096 + 9437184 + 50331648);       // 50.3 MB [b][k][64]
  unsigned short* y       = (unsigned short*)(ws + 4096 + 9437184 + 2*50331648ull);  // 50.3 MB [q][b][64]

  k_maskbias<<<dim3(3), dim3(256), 0, stream>>>(mask, mbias);
  k_pair<<<dim3(768), dim3(256), 0, stream>>>(pair, pscale, pbias, wl, mbias, weights);
  k_act<<<dim3(6144), dim3(256), 0, stream>>>(act, ascale, abias, vproj, wgate, v, gate);
  k_wavg<<<dim3(32, 6, 8), dim3(256), 0, stream>>>(v, weights, y);
  k_final<<<dim3(6144), dim3(256), 0, stream>>>(y, gate, wout, out);
}

// Round 3
// 652.442 us; speedup vs baseline: 1.2469x; 1.2469x over previous
//
#include <hip/hip_runtime.h>
#include <hip/hip_bf16.h>

#define NSEQ 512
#define NRES 768
#define MSAC 64
#define PAIRC 128
#define NHEAD 8

typedef __attribute__((ext_vector_type(8))) short short8_t;
typedef __attribute__((ext_vector_type(4))) float f32x4;

__device__ __forceinline__ float bf2f(unsigned short u){
  return __uint_as_float(((unsigned int)u) << 16);
}
__device__ __forceinline__ unsigned short f2bf(float f){
  unsigned int x = __float_as_uint(f);
  x += 0x7fffu + ((x >> 16) & 1u);   // RTNE
  return (unsigned short)(x >> 16);
}

// ---------------- K0: mask -> additive bias per k ----------------
__global__ void k_maskbias(const float* __restrict__ mask, float* __restrict__ bias){
  int k = blockIdx.x * 256 + threadIdx.x;
  if (k >= NRES) return;
  float m = -1e30f;
  for (int b = 0; b < NSEQ; ++b) m = fmaxf(m, mask[(size_t)b * NRES + k]);
  bias[k] = 1e9f * (bf2f(f2bf(m)) - 1.0f);   // reference casts max to bf16 first
}

// ---------------- K0b: transpose/cast weights to bf16 ----------------
// WvT[j][i] = vproj[i][j]; WgT[j][i] = wgate[j][i]  (both [64][64] bf16)
__global__ void k_prep(const float* __restrict__ vproj, const float* __restrict__ wgate,
                       unsigned short* __restrict__ WvT, unsigned short* __restrict__ WgT){
  int t = blockIdx.x * 256 + threadIdx.x;   // 4096 total
  if (t >= 4096) return;
  int j = t >> 6, i = t & 63;
  WvT[t] = f2bf(vproj[i * 64 + j]);
  WgT[t] = f2bf(wgate[t]);                  // w_gate[j][i] already row=out
}

// ------- K1: pair LN + logits + softmax -> weights bf16 [h][q][k] -------
__global__ __launch_bounds__(256) void k_pair(
    const float* __restrict__ pair, const float* __restrict__ pscale,
    const float* __restrict__ pbias, const float* __restrict__ wl,
    const float* __restrict__ mbias, unsigned short* __restrict__ weights)
{
  __shared__ float lg[NHEAD][NRES];   // 24 KB
  const int q = blockIdx.x;
  const int tid = threadIdx.x;
  const int wv = tid >> 6, lane = tid & 63;
  const int g = lane & 7;
  const int c0 = g * 16;

  float scl[16], bsl[16];
  #pragma unroll
  for (int i = 0; i < 4; ++i){
    float4 s4 = *(const float4*)(pscale + c0 + i*4);
    float4 b4 = *(const float4*)(pbias  + c0 + i*4);
    scl[4*i+0]=s4.x; scl[4*i+1]=s4.y; scl[4*i+2]=s4.z; scl[4*i+3]=s4.w;
    bsl[4*i+0]=b4.x; bsl[4*i+1]=b4.y; bsl[4*i+2]=b4.z; bsl[4*i+3]=b4.w;
  }
  unsigned int wp[8][8];
  #pragma unroll
  for (int h = 0; h < 8; ++h){
    #pragma unroll
    for (int jj = 0; jj < 8; ++jj){
      float2 w2 = *(const float2*)(wl + h*PAIRC + c0 + jj*2);
      wp[h][jj] = (unsigned int)f2bf(w2.x) | ((unsigned int)f2bf(w2.y) << 16);
    }
  }

  for (int it = 0; it < 24; ++it){
    int k = it*32 + wv*8 + (lane >> 3);
    const float* prow = pair + ((size_t)q * NRES + k) * PAIRC + c0;
    float x[16];
    #pragma unroll
    for (int i = 0; i < 4; ++i){
      float4 v4 = *(const float4*)(prow + i*4);
      x[4*i+0]=v4.x; x[4*i+1]=v4.y; x[4*i+2]=v4.z; x[4*i+3]=v4.w;
    }
    float s = 0.f, ss = 0.f;
    #pragma unroll
    for (int i = 0; i < 16; ++i){ s += x[i]; ss += x[i]*x[i]; }
    #pragma unroll
    for (int m = 1; m < 8; m <<= 1){
      s  += __shfl_xor(s,  m, 64);
      ss += __shfl_xor(ss, m, 64);
    }
    float mu  = s * (1.f/128.f);
    float var = ss * (1.f/128.f) - mu*mu;
    float rs  = rsqrtf(var + 1e-5f);
    #pragma unroll
    for (int i = 0; i < 16; ++i) x[i] = (x[i] - mu) * rs * scl[i] + bsl[i];
    float ph[8];
    #pragma unroll
    for (int h = 0; h < 8; ++h){
      float p = 0.f;
      #pragma unroll
      for (int jj = 0; jj < 8; ++jj){
        unsigned int w = wp[h][jj];
        float wlo = __uint_as_float(w << 16);
        float whi = __uint_as_float(w & 0xffff0000u);
        p += x[2*jj] * wlo + x[2*jj+1] * whi;
      }
      ph[h] = p;
    }
    #pragma unroll
    for (int h = 0; h < 8; ++h){
      #pragma unroll
      for (int m = 1; m < 8; m <<= 1) ph[h] += __shfl_xor(ph[h], m, 64);
    }
    #pragma unroll
    for (int h = 0; h < 8; ++h) if (g == h) lg[h][k] = ph[h];
  }
  __syncthreads();
  #pragma unroll
  for (int hh = 0; hh < 2; ++hh){
    int h = wv + hh*4;
    float mx = -1e30f;
    for (int kk = lane; kk < NRES; kk += 64) mx = fmaxf(mx, lg[h][kk] + mbias[kk]);
    #pragma unroll
    for (int m = 1; m < 64; m <<= 1) mx = fmaxf(mx, __shfl_xor(mx, m, 64));
    float sum = 0.f;
    for (int kk = lane; kk < NRES; kk += 64){
      float e = __expf(lg[h][kk] + mbias[kk] - mx);
      lg[h][kk] = e; sum += e;
    }
    #pragma unroll
    for (int m = 1; m < 64; m <<= 1) sum += __shfl_xor(sum, m, 64);
    float inv = 1.0f / sum;
    unsigned short* wrow = weights + ((size_t)h * NRES + q) * NRES;
    for (int kk = lane; kk < NRES; kk += 64) wrow[kk] = f2bf(lg[h][kk] * inv);
  }
}

// ------- K3: act LN + v/gate via register-direct MFMA (no LDS) -------
// 256 thr = 4 waves; wave w owns k-rows w*16..w*16+15 of a 64-row chunk.
// A-fragment pattern loaded straight from global: lane l -> row (l&15),
// i-chunk (l>>4)*8 + s*32. LN stats: 4 lanes share a row -> 2 shfl_xor.
// v: mfma(x, Wv) -> D row=k col=j; gate: mfma(Wg, x) -> D row=j col=k.
__global__ __launch_bounds__(256) void k_act(
    const float* __restrict__ act, const float* __restrict__ ascale,
    const float* __restrict__ abias, const unsigned short* __restrict__ WvT,
    const unsigned short* __restrict__ WgT, unsigned short* __restrict__ v,
    unsigned short* __restrict__ gate)
{
  const int b  = blockIdx.x / 12;
  const int k0 = (blockIdx.x % 12) * 64;
  const int tid = threadIdx.x, w = tid >> 6, lane = tid & 63;
  const int lr = lane & 15;          // A row within wave tile
  const int lc = lane >> 4;          // i-chunk selector (0..3)
  const int row = k0 + w*16 + lr;    // global k row this lane loads

  // load this lane's 16 act elements (fragment pattern)
  const float* arow = act + ((size_t)b*NRES + row)*MSAC;
  float x[2][8];
  #pragma unroll
  for (int s = 0; s < 2; ++s){
    float4 t0 = *(const float4*)(arow + s*32 + lc*8);
    float4 t1 = *(const float4*)(arow + s*32 + lc*8 + 4);
    x[s][0]=t0.x; x[s][1]=t0.y; x[s][2]=t0.z; x[s][3]=t0.w;
    x[s][4]=t1.x; x[s][5]=t1.y; x[s][6]=t1.z; x[s][7]=t1.w;
  }
  // LN stats across the 4 lanes sharing this row (lane ^ 16, ^32)
  float ps = 0.f, pss = 0.f;
  #pragma unroll
  for (int s = 0; s < 2; ++s)
    #pragma unroll
    for (int e = 0; e < 8; ++e){ ps += x[s][e]; pss += x[s][e]*x[s][e]; }
  ps  += __shfl_xor(ps, 16, 64);  pss += __shfl_xor(pss, 16, 64);
  ps  += __shfl_xor(ps, 32, 64);  pss += __shfl_xor(pss, 32, 64);
  const float mu  = ps * (1.f/64.f);
  const float var = pss * (1.f/64.f) - mu*mu;
  const float rs  = rsqrtf(var + 1e-5f);

  // normalize + pack bf16 A-fragments in registers
  short8_t a[2];
  #pragma unroll
  for (int s = 0; s < 2; ++s){
    float4 s0 = *(const float4*)(ascale + s*32 + lc*8);
    float4 s1 = *(const float4*)(ascale + s*32 + lc*8 + 4);
    float4 b0 = *(const float4*)(abias  + s*32 + lc*8);
    float4 b1 = *(const float4*)(abias  + s*32 + lc*8 + 4);
    const float sc[8] = {s0.x,s0.y,s0.z,s0.w,s1.x,s1.y,s1.z,s1.w};
    const float bs[8] = {b0.x,b0.y,b0.z,b0.w,b1.x,b1.y,b1.z,b1.w};
    #pragma unroll
    for (int e = 0; e < 8; ++e)
      a[s][e] = (short)f2bf((x[s][e] - mu)*rs*sc[e] + bs[e]);
  }

  // B-fragments for weights, straight from global (L2-hot 8 KB each)
  short8_t bv[4][2], bg[4][2];
  #pragma unroll
  for (int mf = 0; mf < 4; ++mf){
    #pragma unroll
    for (int s = 0; s < 2; ++s){
      bv[mf][s] = *(const short8_t*)(WvT + (mf*16 + lr)*64 + s*32 + lc*8);
      bg[mf][s] = *(const short8_t*)(WgT + (mf*16 + lr)*64 + s*32 + lc*8);
    }
  }

  f32x4 accv[4], accg[4];
  #pragma unroll
  for (int mf = 0; mf < 4; ++mf){ accv[mf] = 0.f; accg[mf] = 0.f; }
  #pragma unroll
  for (int mf = 0; mf < 4; ++mf){
    #pragma unroll
    for (int s = 0; s < 2; ++s){
      accv[mf] = __builtin_amdgcn_mfma_f32_16x16x32_bf16(a[s], bv[mf][s], accv[mf], 0, 0, 0);
      accg[mf] = __builtin_amdgcn_mfma_f32_16x16x32_bf16(bg[mf][s], a[s], accg[mf], 0, 0, 0);
    }
  }

  // v epilogue: D row=k (lane>>4)*4+e, col=j mf*16+(lane&15)
  const int kv = k0 + w*16 + lc*4;
  #pragma unroll
  for (int mf = 0; mf < 4; ++mf){
    int j = mf*16 + lr;
    int h = j >> 3, c = j & 7;
    ushort4 ov;
    ov.x = f2bf(accv[mf][0]); ov.y = f2bf(accv[mf][1]);
    ov.z = f2bf(accv[mf][2]); ov.w = f2bf(accv[mf][3]);
    *(ushort4*)(v + ((size_t)h*4096 + (size_t)b*8 + c)*NRES + kv) = ov;
  }
  // gate epilogue: D row=j mf*16+(lane>>4)*4+e, col=k (lane&15)
  const int kg = k0 + w*16 + lr;
  #pragma unroll
  for (int mf = 0; mf < 4; ++mf){
    ushort4 og;
    og.x = f2bf(1.0f/(1.0f + __expf(-accg[mf][0])));
    og.y = f2bf(1.0f/(1.0f + __expf(-accg[mf][1])));
    og.z = f2bf(1.0f/(1.0f + __expf(-accg[mf][2])));
    og.w = f2bf(1.0f/(1.0f + __expf(-accg[mf][3])));
    *(ushort4*)(gate + ((size_t)b*NRES + kg)*MSAC + mf*16 + lc*4) = og;
  }
}

// ------- K4: per-head GEMM  Y^T: [bc=4096] x [q=768], K=768, bf16 MFMA -------
__global__ __launch_bounds__(256) void k_wavg(
    const unsigned short* __restrict__ V, const unsigned short* __restrict__ W,
    unsigned short* __restrict__ Y)
{
  __shared__ unsigned char As[128*128];  // [row][128B of k], swizzled
  __shared__ unsigned char Bs[128*128];
  const int h = blockIdx.z, bx = blockIdx.x, by = blockIdx.y;
  const int tid = threadIdx.x, wid = tid >> 6, lane = tid & 63;
  const int wm = wid & 1, wn = wid >> 1;
  const unsigned short* Ag = V + (size_t)h*4096*768 + (size_t)bx*128*768;
  const unsigned short* Bg = W + (size_t)h*768*768 + (size_t)by*128*768;

  f32x4 acc[4][4];
  #pragma unroll
  for (int i=0;i<4;++i){
    #pragma unroll
    for (int jj=0;jj<4;++jj) acc[i][jj] = 0.f;
  }

  uint4 aR[4], bR[4];
  #pragma unroll
  for (int r=0;r<4;++r){
    int cid = tid + r*256, row = cid >> 3, cg = cid & 7;
    aR[r] = *(const uint4*)(Ag + (size_t)row*768 + cg*8);
    bR[r] = *(const uint4*)(Bg + (size_t)row*768 + cg*8);
  }
  for (int kt = 0; kt < 12; ++kt){
    __syncthreads();
    #pragma unroll
    for (int r=0;r<4;++r){
      int cid = tid + r*256, row = cid >> 3, cg = cid & 7;
      int off = row*128 + cg*16; off ^= (row & 7) << 4;
      *(uint4*)(As + off) = aR[r];
      *(uint4*)(Bs + off) = bR[r];
    }
    __syncthreads();
    if (kt < 11){
      #pragma unroll
      for (int r=0;r<4;++r){
        int cid = tid + r*256, row = cid >> 3, cg = cid & 7;
        aR[r] = *(const uint4*)(Ag + (size_t)row*768 + (kt+1)*64 + cg*8);
        bR[r] = *(const uint4*)(Bg + (size_t)row*768 + (kt+1)*64 + cg*8);
      }
    }
    #pragma unroll
    for (int kf = 0; kf < 2; ++kf){
      short8_t af[4], bf[4];
      const int kb = kf*64 + ((lane >> 4) << 4);
      #pragma unroll
      for (int mf = 0; mf < 4; ++mf){
        int row = wm*64 + mf*16 + (lane & 15);
        int off = row*128 + kb; off ^= (row & 7) << 4;
        af[mf] = *(const short8_t*)(As + off);
      }
      #pragma unroll
      for (int nf = 0; nf < 4; ++nf){
        int row = wn*64 + nf*16 + (lane & 15);
        int off = row*128 + kb; off ^= (row & 7) << 4;
        bf[nf] = *(const short8_t*)(Bs + off);
      }
      #pragma unroll
      for (int mf = 0; mf < 4; ++mf){
        #pragma unroll
        for (int nf = 0; nf < 4; ++nf)
          acc[mf][nf] = __builtin_amdgcn_mfma_f32_16x16x32_bf16(af[mf], bf[nf], acc[mf][nf], 0, 0, 0);
      }
    }
  }
  const int q0  = by*128 + wn*64 + (lane & 15);
  const int bc0 = bx*128 + wm*64 + ((lane >> 4) << 2);
  #pragma unroll
  for (int mf = 0; mf < 4; ++mf){
    int bc = bc0 + mf*16;
    size_t obase = (size_t)(bc >> 3)*64 + (size_t)h*8 + (bc & 7);
    #pragma unroll
    for (int nf = 0; nf < 4; ++nf){
      int q = q0 + nf*16;
      f32x4 a = acc[mf][nf];
      ushort4 o;
      o.x = f2bf(a[0]); o.y = f2bf(a[1]); o.z = f2bf(a[2]); o.w = f2bf(a[3]);
      *(ushort4*)(Y + (size_t)q*32768 + obase) = o;
    }
  }
}

// ------- K5: out[b][q][j] = sum_i (y*gate)[i] * w_out[j][i] -------
__global__ __launch_bounds__(256) void k_final(
    const unsigned short* __restrict__ Y, const unsigned short* __restrict__ gate,
    const float* __restrict__ wout, float* __restrict__ out)
{
  __shared__ float wsh[64*68];
  __shared__ float tsh[4][64];
  const int tid = threadIdx.x, wv = tid >> 6, lane = tid & 63;
  for (int i = tid; i < 4096; i += 256) wsh[(i >> 6)*68 + (i & 63)] = wout[i];
  __syncthreads();
  float wr[64];
  #pragma unroll
  for (int i = 0; i < 64; i += 4){
    float4 t = *(const float4*)&wsh[lane*68 + i];
    wr[i]=t.x; wr[i+1]=t.y; wr[i+2]=t.z; wr[i+3]=t.w;
  }
  const int b  = blockIdx.x / 12;
  const int q0 = (blockIdx.x % 12) * 64;
  for (int rr = 0; rr < 16; ++rr){
    int q = q0 + wv*16 + rr;
    float yv = bf2f(Y[((size_t)q*512 + b)*64 + lane]);
    float gv = bf2f(gate[((size_t)b*NRES + q)*64 + lane]);
    tsh[wv][lane] = yv * gv;
    float a = 0.f;
    #pragma unroll
    for (int i = 0; i < 64; i += 4){
      float4 tt = *(const float4*)&tsh[wv][i];
      a += tt.x*wr[i] + tt.y*wr[i+1] + tt.z*wr[i+2] + tt.w*wr[i+3];
    }
    out[((size_t)b*NRES + q)*64 + lane] = a;
  }
}

extern "C" void kernel_launch(void* const* d_in, const int* in_sizes, int n_in,
                              void* d_out, int out_size, void* d_ws, size_t ws_size,
                              hipStream_t stream) {
  (void)in_sizes; (void)n_in; (void)out_size; (void)ws_size;
  const float* act    = (const float*)d_in[0];
  const float* mask   = (const float*)d_in[1];
  const float* pair   = (const float*)d_in[2];
  const float* ascale = (const float*)d_in[3];
  const float* abias  = (const float*)d_in[4];
  const float* pscale = (const float*)d_in[5];
  const float* pbias  = (const float*)d_in[6];
  const float* wl     = (const float*)d_in[7];
  const float* vproj  = (const float*)d_in[8];
  const float* wgate  = (const float*)d_in[9];
  const float* wout   = (const float*)d_in[10];
  float* out = (float*)d_out;

  char* ws = (char*)d_ws;
  float*          mbias   = (float*)(ws);                                   // 3 KB
  unsigned short* WvT     = (unsigned short*)(ws + 4096);                   // 8 KB
  unsigned short* WgT     = (unsigned short*)(ws + 12288);                  // 8 KB
  unsigned short* weights = (unsigned short*)(ws + 24576);                  // 9.4 MB  [h][q][k]
  unsigned short* v       = (unsigned short*)(ws + 24576 + 9437184);        // 50.3 MB [h][bc][k]
  unsigned short* gate    = (unsigned short*)(ws + 24576 + 9437184 + 50331648);       // 50.3 MB [b][k][64]
  unsigned short* y       = (unsigned short*)(ws + 24576 + 9437184 + 2*50331648ull);  // 50.3 MB [q][b][64]

  k_maskbias<<<dim3(3), dim3(256), 0, stream>>>(mask, mbias);
  k_prep<<<dim3(16), dim3(256), 0, stream>>>(vproj, wgate, WvT, WgT);
  k_pair<<<dim3(768), dim3(256), 0, stream>>>(pair, pscale, pbias, wl, mbias, weights);
  k_act<<<dim3(6144), dim3(256), 0, stream>>>(act, ascale, abias, WvT, WgT, v, gate);
  k_wavg<<<dim3(32, 6, 8), dim3(256), 0, stream>>>(v, weights, y);
  k_final<<<dim3(6144), dim3(256), 0, stream>>>(y, gate, wout, out);
}

// Round 4
// 634.226 us; speedup vs baseline: 1.2827x; 1.0287x over previous
//
#include <hip/hip_runtime.h>
#include <hip/hip_bf16.h>

#define NSEQ 512
#define NRES 768
#define MSAC 64
#define PAIRC 128
#define NHEAD 8

typedef __attribute__((ext_vector_type(8))) short short8_t;
typedef __attribute__((ext_vector_type(4))) float f32x4;

__device__ __forceinline__ float bf2f(unsigned short u){
  return __uint_as_float(((unsigned int)u) << 16);
}
__device__ __forceinline__ unsigned short f2bf(float f){
  unsigned int x = __float_as_uint(f);
  x += 0x7fffu + ((x >> 16) & 1u);   // RTNE
  return (unsigned short)(x >> 16);
}

// ---------------- K0: mask -> additive bias per k ----------------
__global__ void k_maskbias(const float* __restrict__ mask, float* __restrict__ bias){
  int k = blockIdx.x * 256 + threadIdx.x;
  if (k >= NRES) return;
  float m = -1e30f;
  for (int b = 0; b < NSEQ; ++b) m = fmaxf(m, mask[(size_t)b * NRES + k]);
  bias[k] = 1e9f * (bf2f(f2bf(m)) - 1.0f);   // reference casts max to bf16 first
}

// ---------------- K0b: transpose/cast weights to bf16 ----------------
// WvT[j][i] = vproj[i][j]; WgT[j][i] = wgate[j][i]  (both [64][64] bf16)
__global__ void k_prep(const float* __restrict__ vproj, const float* __restrict__ wgate,
                       unsigned short* __restrict__ WvT, unsigned short* __restrict__ WgT){
  int t = blockIdx.x * 256 + threadIdx.x;   // 4096 total
  if (t >= 4096) return;
  int j = t >> 6, i = t & 63;
  WvT[t] = f2bf(vproj[i * 64 + j]);
  WgT[t] = f2bf(wgate[t]);                  // w_gate[j][i] already row=out
}

// ------- K1: pair LN + logits + softmax -> weights bf16 [h][q][k] -------
__global__ __launch_bounds__(256) void k_pair(
    const float* __restrict__ pair, const float* __restrict__ pscale,
    const float* __restrict__ pbias, const float* __restrict__ wl,
    const float* __restrict__ mbias, unsigned short* __restrict__ weights)
{
  __shared__ float lg[NHEAD][NRES];   // 24 KB
  const int q = blockIdx.x;
  const int tid = threadIdx.x;
  const int wv = tid >> 6, lane = tid & 63;
  const int g = lane & 7;
  const int c0 = g * 16;

  float scl[16], bsl[16];
  #pragma unroll
  for (int i = 0; i < 4; ++i){
    float4 s4 = *(const float4*)(pscale + c0 + i*4);
    float4 b4 = *(const float4*)(pbias  + c0 + i*4);
    scl[4*i+0]=s4.x; scl[4*i+1]=s4.y; scl[4*i+2]=s4.z; scl[4*i+3]=s4.w;
    bsl[4*i+0]=b4.x; bsl[4*i+1]=b4.y; bsl[4*i+2]=b4.z; bsl[4*i+3]=b4.w;
  }
  unsigned int wp[8][8];
  #pragma unroll
  for (int h = 0; h < 8; ++h){
    #pragma unroll
    for (int jj = 0; jj < 8; ++jj){
      float2 w2 = *(const float2*)(wl + h*PAIRC + c0 + jj*2);
      wp[h][jj] = (unsigned int)f2bf(w2.x) | ((unsigned int)f2bf(w2.y) << 16);
    }
  }

  for (int it = 0; it < 24; ++it){
    int k = it*32 + wv*8 + (lane >> 3);
    const float* prow = pair + ((size_t)q * NRES + k) * PAIRC + c0;
    float x[16];
    #pragma unroll
    for (int i = 0; i < 4; ++i){
      float4 v4 = *(const float4*)(prow + i*4);
      x[4*i+0]=v4.x; x[4*i+1]=v4.y; x[4*i+2]=v4.z; x[4*i+3]=v4.w;
    }
    float s = 0.f, ss = 0.f;
    #pragma unroll
    for (int i = 0; i < 16; ++i){ s += x[i]; ss += x[i]*x[i]; }
    #pragma unroll
    for (int m = 1; m < 8; m <<= 1){
      s  += __shfl_xor(s,  m, 64);
      ss += __shfl_xor(ss, m, 64);
    }
    float mu  = s * (1.f/128.f);
    float var = ss * (1.f/128.f) - mu*mu;
    float rs  = rsqrtf(var + 1e-5f);
    #pragma unroll
    for (int i = 0; i < 16; ++i) x[i] = (x[i] - mu) * rs * scl[i] + bsl[i];
    float ph[8];
    #pragma unroll
    for (int h = 0; h < 8; ++h){
      float p = 0.f;
      #pragma unroll
      for (int jj = 0; jj < 8; ++jj){
        unsigned int w = wp[h][jj];
        float wlo = __uint_as_float(w << 16);
        float whi = __uint_as_float(w & 0xffff0000u);
        p += x[2*jj] * wlo + x[2*jj+1] * whi;
      }
      ph[h] = p;
    }
    #pragma unroll
    for (int h = 0; h < 8; ++h){
      #pragma unroll
      for (int m = 1; m < 8; m <<= 1) ph[h] += __shfl_xor(ph[h], m, 64);
    }
    #pragma unroll
    for (int h = 0; h < 8; ++h) if (g == h) lg[h][k] = ph[h];
  }
  __syncthreads();
  #pragma unroll
  for (int hh = 0; hh < 2; ++hh){
    int h = wv + hh*4;
    float mx = -1e30f;
    for (int kk = lane; kk < NRES; kk += 64) mx = fmaxf(mx, lg[h][kk] + mbias[kk]);
    #pragma unroll
    for (int m = 1; m < 64; m <<= 1) mx = fmaxf(mx, __shfl_xor(mx, m, 64));
    float sum = 0.f;
    for (int kk = lane; kk < NRES; kk += 64){
      float e = __expf(lg[h][kk] + mbias[kk] - mx);
      lg[h][kk] = e; sum += e;
    }
    #pragma unroll
    for (int m = 1; m < 64; m <<= 1) sum += __shfl_xor(sum, m, 64);
    float inv = 1.0f / sum;
    unsigned short* wrow = weights + ((size_t)h * NRES + q) * NRES;
    for (int kk = lane; kk < NRES; kk += 64) wrow[kk] = f2bf(lg[h][kk] * inv);
  }
}

// ------- K3: act LN + v/gate via register-direct MFMA (no LDS) -------
__global__ __launch_bounds__(256) void k_act(
    const float* __restrict__ act, const float* __restrict__ ascale,
    const float* __restrict__ abias, const unsigned short* __restrict__ WvT,
    const unsigned short* __restrict__ WgT, unsigned short* __restrict__ v,
    unsigned short* __restrict__ gate)
{
  const int b  = blockIdx.x / 12;
  const int k0 = (blockIdx.x % 12) * 64;
  const int tid = threadIdx.x, w = tid >> 6, lane = tid & 63;
  const int lr = lane & 15;          // A row within wave tile
  const int lc = lane >> 4;          // i-chunk selector (0..3)
  const int row = k0 + w*16 + lr;    // global k row this lane loads

  const float* arow = act + ((size_t)b*NRES + row)*MSAC;
  float x[2][8];
  #pragma unroll
  for (int s = 0; s < 2; ++s){
    float4 t0 = *(const float4*)(arow + s*32 + lc*8);
    float4 t1 = *(const float4*)(arow + s*32 + lc*8 + 4);
    x[s][0]=t0.x; x[s][1]=t0.y; x[s][2]=t0.z; x[s][3]=t0.w;
    x[s][4]=t1.x; x[s][5]=t1.y; x[s][6]=t1.z; x[s][7]=t1.w;
  }
  float ps = 0.f, pss = 0.f;
  #pragma unroll
  for (int s = 0; s < 2; ++s)
    #pragma unroll
    for (int e = 0; e < 8; ++e){ ps += x[s][e]; pss += x[s][e]*x[s][e]; }
  ps  += __shfl_xor(ps, 16, 64);  pss += __shfl_xor(pss, 16, 64);
  ps  += __shfl_xor(ps, 32, 64);  pss += __shfl_xor(pss, 32, 64);
  const float mu  = ps * (1.f/64.f);
  const float var = pss * (1.f/64.f) - mu*mu;
  const float rs  = rsqrtf(var + 1e-5f);

  short8_t a[2];
  #pragma unroll
  for (int s = 0; s < 2; ++s){
    float4 s0 = *(const float4*)(ascale + s*32 + lc*8);
    float4 s1 = *(const float4*)(ascale + s*32 + lc*8 + 4);
    float4 b0 = *(const float4*)(abias  + s*32 + lc*8);
    float4 b1 = *(const float4*)(abias  + s*32 + lc*8 + 4);
    const float sc[8] = {s0.x,s0.y,s0.z,s0.w,s1.x,s1.y,s1.z,s1.w};
    const float bs[8] = {b0.x,b0.y,b0.z,b0.w,b1.x,b1.y,b1.z,b1.w};
    #pragma unroll
    for (int e = 0; e < 8; ++e)
      a[s][e] = (short)f2bf((x[s][e] - mu)*rs*sc[e] + bs[e]);
  }

  short8_t bv[4][2], bg[4][2];
  #pragma unroll
  for (int mf = 0; mf < 4; ++mf){
    #pragma unroll
    for (int s = 0; s < 2; ++s){
      bv[mf][s] = *(const short8_t*)(WvT + (mf*16 + lr)*64 + s*32 + lc*8);
      bg[mf][s] = *(const short8_t*)(WgT + (mf*16 + lr)*64 + s*32 + lc*8);
    }
  }

  f32x4 accv[4], accg[4];
  #pragma unroll
  for (int mf = 0; mf < 4; ++mf){ accv[mf] = 0.f; accg[mf] = 0.f; }
  #pragma unroll
  for (int mf = 0; mf < 4; ++mf){
    #pragma unroll
    for (int s = 0; s < 2; ++s){
      accv[mf] = __builtin_amdgcn_mfma_f32_16x16x32_bf16(a[s], bv[mf][s], accv[mf], 0, 0, 0);
      accg[mf] = __builtin_amdgcn_mfma_f32_16x16x32_bf16(bg[mf][s], a[s], accg[mf], 0, 0, 0);
    }
  }

  const int kv = k0 + w*16 + lc*4;
  #pragma unroll
  for (int mf = 0; mf < 4; ++mf){
    int j = mf*16 + lr;
    int h = j >> 3, c = j & 7;
    ushort4 ov;
    ov.x = f2bf(accv[mf][0]); ov.y = f2bf(accv[mf][1]);
    ov.z = f2bf(accv[mf][2]); ov.w = f2bf(accv[mf][3]);
    *(ushort4*)(v + ((size_t)h*4096 + (size_t)b*8 + c)*NRES + kv) = ov;
  }
  const int kg = k0 + w*16 + lr;
  #pragma unroll
  for (int mf = 0; mf < 4; ++mf){
    ushort4 og;
    og.x = f2bf(1.0f/(1.0f + __expf(-accg[mf][0])));
    og.y = f2bf(1.0f/(1.0f + __expf(-accg[mf][1])));
    og.z = f2bf(1.0f/(1.0f + __expf(-accg[mf][2])));
    og.w = f2bf(1.0f/(1.0f + __expf(-accg[mf][3])));
    *(ushort4*)(gate + ((size_t)b*NRES + kg)*MSAC + mf*16 + lc*4) = og;
  }
}

// ------- K4: per-head GEMM  Y2[q][h][b][c] = weights[h] @ v[h] -------
// 1536 blocks, XCD-chunked swizzle (each XCD -> one head). 128x128x64 tiles.
// Epilogue: D -> swizzled LDS (aliases As/Bs) -> 16B-coalesced 256B-row stores.
__global__ __launch_bounds__(256) void k_wavg(
    const unsigned short* __restrict__ V, const unsigned short* __restrict__ W,
    unsigned short* __restrict__ Y)
{
  __shared__ unsigned char smem[32768];
  unsigned char* As = smem;            // 16 KB [row][128B of k], swizzled
  unsigned char* Bs = smem + 16384;    // 16 KB

  // XCD-chunked swizzle: flat ids 0..1535, xcd = flat&7 gets chunk of 192
  const int flat = blockIdx.x;
  const int nid  = (flat & 7) * 192 + (flat >> 3);
  const int bx = nid & 31;            // 32 bc-tiles
  const int by = (nid >> 5) % 6;      // 6 q-tiles
  const int h  = nid / 192;           // 8 heads (== xcd)

  const int tid = threadIdx.x, wid = tid >> 6, lane = tid & 63;
  const int wm = wid & 1, wn = wid >> 1;
  const unsigned short* Ag = V + (size_t)h*4096*768 + (size_t)bx*128*768;
  const unsigned short* Bg = W + (size_t)h*768*768 + (size_t)by*128*768;

  f32x4 acc[4][4];
  #pragma unroll
  for (int i=0;i<4;++i){
    #pragma unroll
    for (int jj=0;jj<4;++jj) acc[i][jj] = 0.f;
  }

  uint4 aR[4], bR[4];
  #pragma unroll
  for (int r=0;r<4;++r){
    int cid = tid + r*256, row = cid >> 3, cg = cid & 7;
    aR[r] = *(const uint4*)(Ag + (size_t)row*768 + cg*8);
    bR[r] = *(const uint4*)(Bg + (size_t)row*768 + cg*8);
  }
  for (int kt = 0; kt < 12; ++kt){
    __syncthreads();
    #pragma unroll
    for (int r=0;r<4;++r){
      int cid = tid + r*256, row = cid >> 3, cg = cid & 7;
      int off = row*128 + cg*16; off ^= (row & 7) << 4;
      *(uint4*)(As + off) = aR[r];
      *(uint4*)(Bs + off) = bR[r];
    }
    __syncthreads();
    if (kt < 11){
      #pragma unroll
      for (int r=0;r<4;++r){
        int cid = tid + r*256, row = cid >> 3, cg = cid & 7;
        aR[r] = *(const uint4*)(Ag + (size_t)row*768 + (kt+1)*64 + cg*8);
        bR[r] = *(const uint4*)(Bg + (size_t)row*768 + (kt+1)*64 + cg*8);
      }
    }
    #pragma unroll
    for (int kf = 0; kf < 2; ++kf){
      short8_t af[4], bf[4];
      const int kb = kf*64 + ((lane >> 4) << 4);
      #pragma unroll
      for (int mf = 0; mf < 4; ++mf){
        int row = wm*64 + mf*16 + (lane & 15);
        int off = row*128 + kb; off ^= (row & 7) << 4;
        af[mf] = *(const short8_t*)(As + off);
      }
      #pragma unroll
      for (int nf = 0; nf < 4; ++nf){
        int row = wn*64 + nf*16 + (lane & 15);
        int off = row*128 + kb; off ^= (row & 7) << 4;
        bf[nf] = *(const short8_t*)(Bs + off);
      }
      #pragma unroll
      for (int mf = 0; mf < 4; ++mf){
        #pragma unroll
        for (int nf = 0; nf < 4; ++nf)
          acc[mf][nf] = __builtin_amdgcn_mfma_f32_16x16x32_bf16(af[mf], bf[nf], acc[mf][nf], 0, 0, 0);
      }
    }
  }
  // ---- epilogue: stage D tile in LDS (alias As/Bs), then coalesced stores ----
  __syncthreads();                       // all LDS reads done before overwrite
  unsigned char* Ds = smem;              // 32 KB: [q_local 128][bc_local 128] bf16
  #pragma unroll
  for (int mf = 0; mf < 4; ++mf){
    int bc = wm*64 + mf*16 + ((lane >> 4) << 2);
    #pragma unroll
    for (int nf = 0; nf < 4; ++nf){
      int q = wn*64 + nf*16 + (lane & 15);
      f32x4 a = acc[mf][nf];
      ushort4 o;
      o.x = f2bf(a[0]); o.y = f2bf(a[1]); o.z = f2bf(a[2]); o.w = f2bf(a[3]);
      int off = q*256 + bc*2; off ^= (q & 7) << 4;
      *(ushort4*)(Ds + off) = o;
    }
  }
  __syncthreads();
  // Y2[q][h][b][c]: block's per-q segment is 256B contiguous at h*4096 + bx*128
  #pragma unroll
  for (int it = 0; it < 8; ++it){
    int fl = it*256 + tid;
    int q = fl >> 4, chunk = fl & 15;
    int off = q*256 + chunk*16; off ^= (q & 7) << 4;
    uint4 val = *(const uint4*)(Ds + off);
    *(uint4*)(Y + (size_t)(by*128 + q)*32768 + h*4096 + bx*128 + chunk*8) = val;
  }
}

// ------- K5: out[b][q][j] = sum_i (y*gate)[i] * w_out[j][i] -------
// grid b-fastest so neighbor blocks share Y2 lines through L2/L3.
__global__ __launch_bounds__(256) void k_final(
    const unsigned short* __restrict__ Y, const unsigned short* __restrict__ gate,
    const float* __restrict__ wout, float* __restrict__ out)
{
  __shared__ float wsh[64*68];
  __shared__ float tsh[4][64];
  const int tid = threadIdx.x, wv = tid >> 6, lane = tid & 63;
  for (int i = tid; i < 4096; i += 256) wsh[(i >> 6)*68 + (i & 63)] = wout[i];
  __syncthreads();
  float wr[64];
  #pragma unroll
  for (int i = 0; i < 64; i += 4){
    float4 t = *(const float4*)&wsh[lane*68 + i];
    wr[i]=t.x; wr[i+1]=t.y; wr[i+2]=t.z; wr[i+3]=t.w;
  }
  const int b  = blockIdx.x & 511;
  const int q0 = (blockIdx.x >> 9) * 64;
  const int hh = lane >> 3, cc = lane & 7;   // j = lane decomposition
  for (int rr = 0; rr < 16; ++rr){
    int q = q0 + wv*16 + rr;
    float yv = bf2f(Y[(size_t)q*32768 + hh*4096 + b*8 + cc]);
    float gv = bf2f(gate[((size_t)b*NRES + q)*64 + lane]);
    tsh[wv][lane] = yv * gv;
    float a = 0.f;
    #pragma unroll
    for (int i = 0; i < 64; i += 4){
      float4 tt = *(const float4*)&tsh[wv][i];
      a += tt.x*wr[i] + tt.y*wr[i+1] + tt.z*wr[i+2] + tt.w*wr[i+3];
    }
    out[((size_t)b*NRES + q)*64 + lane] = a;
  }
}

extern "C" void kernel_launch(void* const* d_in, const int* in_sizes, int n_in,
                              void* d_out, int out_size, void* d_ws, size_t ws_size,
                              hipStream_t stream) {
  (void)in_sizes; (void)n_in; (void)out_size; (void)ws_size;
  const float* act    = (const float*)d_in[0];
  const float* mask   = (const float*)d_in[1];
  const float* pair   = (const float*)d_in[2];
  const float* ascale = (const float*)d_in[3];
  const float* abias  = (const float*)d_in[4];
  const float* pscale = (const float*)d_in[5];
  const float* pbias  = (const float*)d_in[6];
  const float* wl     = (const float*)d_in[7];
  const float* vproj  = (const float*)d_in[8];
  const float* wgate  = (const float*)d_in[9];
  const float* wout   = (const float*)d_in[10];
  float* out = (float*)d_out;

  char* ws = (char*)d_ws;
  float*          mbias   = (float*)(ws);                                   // 3 KB
  unsigned short* WvT     = (unsigned short*)(ws + 4096);                   // 8 KB
  unsigned short* WgT     = (unsigned short*)(ws + 12288);                  // 8 KB
  unsigned short* weights = (unsigned short*)(ws + 24576);                  // 9.4 MB  [h][q][k]
  unsigned short* v       = (unsigned short*)(ws + 24576 + 9437184);        // 50.3 MB [h][bc][k]
  unsigned short* gate    = (unsigned short*)(ws + 24576 + 9437184 + 50331648);       // 50.3 MB [b][k][64]
  unsigned short* y       = (unsigned short*)(ws + 24576 + 9437184 + 2*50331648ull);  // 50.3 MB [q][h][b][c]

  k_maskbias<<<dim3(3), dim3(256), 0, stream>>>(mask, mbias);
  k_prep<<<dim3(16), dim3(256), 0, stream>>>(vproj, wgate, WvT, WgT);
  k_pair<<<dim3(768), dim3(256), 0, stream>>>(pair, pscale, pbias, wl, mbias, weights);
  k_act<<<dim3(6144), dim3(256), 0, stream>>>(act, ascale, abias, WvT, WgT, v, gate);
  k_wavg<<<dim3(1536), dim3(256), 0, stream>>>(v, weights, y);
  k_final<<<dim3(6144), dim3(256), 0, stream>>>(y, gate, wout, out);
}

// Round 5
// 475.095 us; speedup vs baseline: 1.7124x; 1.3349x over previous
//
#include <hip/hip_runtime.h>
#include <hip/hip_bf16.h>

#define NSEQ 512
#define NRES 768
#define MSAC 64
#define PAIRC 128
#define NHEAD 8

typedef __attribute__((ext_vector_type(8))) short short8_t;
typedef __attribute__((ext_vector_type(4))) float f32x4;

__device__ __forceinline__ float bf2f(unsigned short u){
  return __uint_as_float(((unsigned int)u) << 16);
}
__device__ __forceinline__ unsigned short f2bf(float f){
  unsigned int x = __float_as_uint(f);
  x += 0x7fffu + ((x >> 16) & 1u);   // RTNE
  return (unsigned short)(x >> 16);
}
// async global->LDS, 16B per lane; lds base must be wave-uniform (lane*16 implicit)
__device__ __forceinline__ void glds16(const void* g, void* l){
  __builtin_amdgcn_global_load_lds(
      (const __attribute__((address_space(1))) unsigned int*)g,
      (__attribute__((address_space(3))) unsigned int*)l, 16, 0, 0);
}

// ---------------- K0: mask -> additive bias per k ----------------
__global__ void k_maskbias(const float* __restrict__ mask, float* __restrict__ bias){
  int k = blockIdx.x * 256 + threadIdx.x;
  if (k >= NRES) return;
  float m = -1e30f;
  for (int b = 0; b < NSEQ; ++b) m = fmaxf(m, mask[(size_t)b * NRES + k]);
  bias[k] = 1e9f * (bf2f(f2bf(m)) - 1.0f);   // reference casts max to bf16 first
}

// ---------------- K0b: transpose/cast weights to bf16 ----------------
__global__ void k_prep(const float* __restrict__ vproj, const float* __restrict__ wgate,
                       unsigned short* __restrict__ WvT, unsigned short* __restrict__ WgT){
  int t = blockIdx.x * 256 + threadIdx.x;   // 4096 total
  if (t >= 4096) return;
  int j = t >> 6, i = t & 63;
  WvT[t] = f2bf(vproj[i * 64 + j]);
  WgT[t] = f2bf(wgate[t]);                  // w_gate[j][i] already row=out
}

// ------- K1: pair LN + logits + softmax -> weights bf16 [h][q][k] -------
__global__ __launch_bounds__(256) void k_pair(
    const float* __restrict__ pair, const float* __restrict__ pscale,
    const float* __restrict__ pbias, const float* __restrict__ wl,
    const float* __restrict__ mbias, unsigned short* __restrict__ weights)
{
  __shared__ float lg[NHEAD][NRES];   // 24 KB
  const int q = blockIdx.x;
  const int tid = threadIdx.x;
  const int wv = tid >> 6, lane = tid & 63;
  const int g = lane & 7;
  const int c0 = g * 16;

  float scl[16], bsl[16];
  #pragma unroll
  for (int i = 0; i < 4; ++i){
    float4 s4 = *(const float4*)(pscale + c0 + i*4);
    float4 b4 = *(const float4*)(pbias  + c0 + i*4);
    scl[4*i+0]=s4.x; scl[4*i+1]=s4.y; scl[4*i+2]=s4.z; scl[4*i+3]=s4.w;
    bsl[4*i+0]=b4.x; bsl[4*i+1]=b4.y; bsl[4*i+2]=b4.z; bsl[4*i+3]=b4.w;
  }
  unsigned int wp[8][8];
  #pragma unroll
  for (int h = 0; h < 8; ++h){
    #pragma unroll
    for (int jj = 0; jj < 8; ++jj){
      float2 w2 = *(const float2*)(wl + h*PAIRC + c0 + jj*2);
      wp[h][jj] = (unsigned int)f2bf(w2.x) | ((unsigned int)f2bf(w2.y) << 16);
    }
  }

  for (int it = 0; it < 24; ++it){
    int k = it*32 + wv*8 + (lane >> 3);
    const float* prow = pair + ((size_t)q * NRES + k) * PAIRC + c0;
    float x[16];
    #pragma unroll
    for (int i = 0; i < 4; ++i){
      float4 v4 = *(const float4*)(prow + i*4);
      x[4*i+0]=v4.x; x[4*i+1]=v4.y; x[4*i+2]=v4.z; x[4*i+3]=v4.w;
    }
    float s = 0.f, ss = 0.f;
    #pragma unroll
    for (int i = 0; i < 16; ++i){ s += x[i]; ss += x[i]*x[i]; }
    #pragma unroll
    for (int m = 1; m < 8; m <<= 1){
      s  += __shfl_xor(s,  m, 64);
      ss += __shfl_xor(ss, m, 64);
    }
    float mu  = s * (1.f/128.f);
    float var = ss * (1.f/128.f) - mu*mu;
    float rs  = rsqrtf(var + 1e-5f);
    #pragma unroll
    for (int i = 0; i < 16; ++i) x[i] = (x[i] - mu) * rs * scl[i] + bsl[i];
    float ph[8];
    #pragma unroll
    for (int h = 0; h < 8; ++h){
      float p = 0.f;
      #pragma unroll
      for (int jj = 0; jj < 8; ++jj){
        unsigned int w = wp[h][jj];
        float wlo = __uint_as_float(w << 16);
        float whi = __uint_as_float(w & 0xffff0000u);
        p += x[2*jj] * wlo + x[2*jj+1] * whi;
      }
      ph[h] = p;
    }
    #pragma unroll
    for (int h = 0; h < 8; ++h){
      #pragma unroll
      for (int m = 1; m < 8; m <<= 1) ph[h] += __shfl_xor(ph[h], m, 64);
    }
    #pragma unroll
    for (int h = 0; h < 8; ++h) if (g == h) lg[h][k] = ph[h];
  }
  __syncthreads();
  #pragma unroll
  for (int hh = 0; hh < 2; ++hh){
    int h = wv + hh*4;
    float mx = -1e30f;
    for (int kk = lane; kk < NRES; kk += 64) mx = fmaxf(mx, lg[h][kk] + mbias[kk]);
    #pragma unroll
    for (int m = 1; m < 64; m <<= 1) mx = fmaxf(mx, __shfl_xor(mx, m, 64));
    float sum = 0.f;
    for (int kk = lane; kk < NRES; kk += 64){
      float e = __expf(lg[h][kk] + mbias[kk] - mx);
      lg[h][kk] = e; sum += e;
    }
    #pragma unroll
    for (int m = 1; m < 64; m <<= 1) sum += __shfl_xor(sum, m, 64);
    float inv = 1.0f / sum;
    unsigned short* wrow = weights + ((size_t)h * NRES + q) * NRES;
    for (int kk = lane; kk < NRES; kk += 64) wrow[kk] = f2bf(lg[h][kk] * inv);
  }
}

// ------- K3: act LN + v/gate via register-direct MFMA (no LDS) -------
__global__ __launch_bounds__(256) void k_act(
    const float* __restrict__ act, const float* __restrict__ ascale,
    const float* __restrict__ abias, const unsigned short* __restrict__ WvT,
    const unsigned short* __restrict__ WgT, unsigned short* __restrict__ v,
    unsigned short* __restrict__ gate)
{
  const int b  = blockIdx.x / 12;
  const int k0 = (blockIdx.x % 12) * 64;
  const int tid = threadIdx.x, w = tid >> 6, lane = tid & 63;
  const int lr = lane & 15;          // A row within wave tile
  const int lc = lane >> 4;          // i-chunk selector (0..3)
  const int row = k0 + w*16 + lr;    // global k row this lane loads

  const float* arow = act + ((size_t)b*NRES + row)*MSAC;
  float x[2][8];
  #pragma unroll
  for (int s = 0; s < 2; ++s){
    float4 t0 = *(const float4*)(arow + s*32 + lc*8);
    float4 t1 = *(const float4*)(arow + s*32 + lc*8 + 4);
    x[s][0]=t0.x; x[s][1]=t0.y; x[s][2]=t0.z; x[s][3]=t0.w;
    x[s][4]=t1.x; x[s][5]=t1.y; x[s][6]=t1.z; x[s][7]=t1.w;
  }
  float ps = 0.f, pss = 0.f;
  #pragma unroll
  for (int s = 0; s < 2; ++s)
    #pragma unroll
    for (int e = 0; e < 8; ++e){ ps += x[s][e]; pss += x[s][e]*x[s][e]; }
  ps  += __shfl_xor(ps, 16, 64);  pss += __shfl_xor(pss, 16, 64);
  ps  += __shfl_xor(ps, 32, 64);  pss += __shfl_xor(pss, 32, 64);
  const float mu  = ps * (1.f/64.f);
  const float var = pss * (1.f/64.f) - mu*mu;
  const float rs  = rsqrtf(var + 1e-5f);

  short8_t a[2];
  #pragma unroll
  for (int s = 0; s < 2; ++s){
    float4 s0 = *(const float4*)(ascale + s*32 + lc*8);
    float4 s1 = *(const float4*)(ascale + s*32 + lc*8 + 4);
    float4 b0 = *(const float4*)(abias  + s*32 + lc*8);
    float4 b1 = *(const float4*)(abias  + s*32 + lc*8 + 4);
    const float sc[8] = {s0.x,s0.y,s0.z,s0.w,s1.x,s1.y,s1.z,s1.w};
    const float bs[8] = {b0.x,b0.y,b0.z,b0.w,b1.x,b1.y,b1.z,b1.w};
    #pragma unroll
    for (int e = 0; e < 8; ++e)
      a[s][e] = (short)f2bf((x[s][e] - mu)*rs*sc[e] + bs[e]);
  }

  short8_t bv[4][2], bg[4][2];
  #pragma unroll
  for (int mf = 0; mf < 4; ++mf){
    #pragma unroll
    for (int s = 0; s < 2; ++s){
      bv[mf][s] = *(const short8_t*)(WvT + (mf*16 + lr)*64 + s*32 + lc*8);
      bg[mf][s] = *(const short8_t*)(WgT + (mf*16 + lr)*64 + s*32 + lc*8);
    }
  }

  f32x4 accv[4], accg[4];
  #pragma unroll
  for (int mf = 0; mf < 4; ++mf){ accv[mf] = 0.f; accg[mf] = 0.f; }
  #pragma unroll
  for (int mf = 0; mf < 4; ++mf){
    #pragma unroll
    for (int s = 0; s < 2; ++s){
      accv[mf] = __builtin_amdgcn_mfma_f32_16x16x32_bf16(a[s], bv[mf][s], accv[mf], 0, 0, 0);
      accg[mf] = __builtin_amdgcn_mfma_f32_16x16x32_bf16(bg[mf][s], a[s], accg[mf], 0, 0, 0);
    }
  }

  const int kv = k0 + w*16 + lc*4;
  #pragma unroll
  for (int mf = 0; mf < 4; ++mf){
    int j = mf*16 + lr;
    int h = j >> 3, c = j & 7;
    ushort4 ov;
    ov.x = f2bf(accv[mf][0]); ov.y = f2bf(accv[mf][1]);
    ov.z = f2bf(accv[mf][2]); ov.w = f2bf(accv[mf][3]);
    *(ushort4*)(v + ((size_t)h*4096 + (size_t)b*8 + c)*NRES + kv) = ov;
  }
  const int kg = k0 + w*16 + lr;
  #pragma unroll
  for (int mf = 0; mf < 4; ++mf){
    ushort4 og;
    og.x = f2bf(1.0f/(1.0f + __expf(-accg[mf][0])));
    og.y = f2bf(1.0f/(1.0f + __expf(-accg[mf][1])));
    og.z = f2bf(1.0f/(1.0f + __expf(-accg[mf][2])));
    og.w = f2bf(1.0f/(1.0f + __expf(-accg[mf][3])));
    *(ushort4*)(gate + ((size_t)b*NRES + kg)*MSAC + mf*16 + lc*4) = og;
  }
}

// ------- K4: per-head GEMM  Y3[h][bx][q][cl] = weights[h] @ v[h] -------
// m97 structure: global_load_lds(16B) staging w/ pre-swizzled source, 2 barriers
// per K-step, 32 KB LDS (5 blocks/CU). XCD-chunked head mapping, by-fastest for
// A-tile reuse (B panel 1.18 MB stays L2-resident per head/XCD).
__global__ __launch_bounds__(256) void k_wavg(
    const unsigned short* __restrict__ V, const unsigned short* __restrict__ W,
    unsigned short* __restrict__ Y)
{
  __shared__ unsigned char smem[32768];
  unsigned char* As = smem;            // 16 KB [row 128][128B of k], swizzled
  unsigned char* Bs = smem + 16384;    // 16 KB

  const int flat = blockIdx.x;
  const int nid  = (flat & 7) * 192 + (flat >> 3);   // XCD chunk of 192 = 1 head
  const int m    = nid % 192;
  const int by   = m % 6;              // fastest: A-tile reuse across 6 blocks
  const int bx   = m / 6;
  const int h    = nid / 192;

  const int tid = threadIdx.x, wid = tid >> 6, lane = tid & 63;
  const int wm = wid & 1, wn = wid >> 1;
  const unsigned short* Ag = V + (size_t)h*4096*768 + (size_t)bx*128*768;
  const unsigned short* Bg = W + (size_t)h*768*768 + (size_t)by*128*768;

  f32x4 acc[4][4];
  #pragma unroll
  for (int i=0;i<4;++i){
    #pragma unroll
    for (int jj=0;jj<4;++jj) acc[i][jj] = 0.f;
  }

  // staging geometry: linear LDS pos cid*16 (cid = wid*256 + r*64 + lane),
  // row = cid>>3, chunk = cid&7; source col-chunk = chunk ^ (row&7)  (involution
  // matching the ds_read swizzle). lds base wave-uniform; lane*16 implicit.
  const int srow0 = wid * 32;                       // 32 rows per wave quarter
  for (int kt = 0; kt < 12; ++kt){
    __syncthreads();                                // prev reads done
    #pragma unroll
    for (int r = 0; r < 4; ++r){
      int cid = (srow0 + r*8) * 8 + lane;           // = wid*256 + r*64 + lane
      int row = cid >> 3, ch = cid & 7;
      int sc = ch ^ (row & 7);
      glds16(Ag + (size_t)row*768 + kt*64 + sc*8, As + cid*16 - lane*16);
      glds16(Bg + (size_t)row*768 + kt*64 + sc*8, Bs + cid*16 - lane*16);
    }
    __syncthreads();                                // staging complete (vmcnt drain)
    #pragma unroll
    for (int kf = 0; kf < 2; ++kf){
      short8_t af[4], bf[4];
      const int kb = kf*64 + ((lane >> 4) << 4);
      #pragma unroll
      for (int mf = 0; mf < 4; ++mf){
        int row = wm*64 + mf*16 + (lane & 15);
        int off = row*128 + kb; off ^= (row & 7) << 4;
        af[mf] = *(const short8_t*)(As + off);
      }
      #pragma unroll
      for (int nf = 0; nf < 4; ++nf){
        int row = wn*64 + nf*16 + (lane & 15);
        int off = row*128 + kb; off ^= (row & 7) << 4;
        bf[nf] = *(const short8_t*)(Bs + off);
      }
      #pragma unroll
      for (int mf = 0; mf < 4; ++mf){
        #pragma unroll
        for (int nf = 0; nf < 4; ++nf)
          acc[mf][nf] = __builtin_amdgcn_mfma_f32_16x16x32_bf16(af[mf], bf[nf], acc[mf][nf], 0, 0, 0);
      }
    }
  }
  // ---- epilogue: D -> swizzled LDS -> fully-contiguous 32 KB block store ----
  __syncthreads();
  unsigned char* Ds = smem;              // 32 KB: [q_local 128][bc_local 128] bf16
  #pragma unroll
  for (int mf = 0; mf < 4; ++mf){
    int bc = wm*64 + mf*16 + ((lane >> 4) << 2);
    #pragma unroll
    for (int nf = 0; nf < 4; ++nf){
      int q = wn*64 + nf*16 + (lane & 15);
      f32x4 a = acc[mf][nf];
      ushort4 o;
      o.x = f2bf(a[0]); o.y = f2bf(a[1]); o.z = f2bf(a[2]); o.w = f2bf(a[3]);
      int off = q*256 + bc*2; off ^= (q & 7) << 4;
      *(ushort4*)(Ds + off) = o;
    }
  }
  __syncthreads();
  // Y3[h][bx][q][cl]: block region = ((h*32+bx)*768 + by*128)*128 shorts, 32 KB contig
  unsigned short* Yb = Y + ((size_t)(h*32 + bx)*768 + by*128)*128;
  #pragma unroll
  for (int it = 0; it < 8; ++it){
    int fl = it*256 + tid;
    int q = fl >> 4, chunk = fl & 15;
    int off = q*256 + chunk*16; off ^= (q & 7) << 4;
    uint4 val = *(const uint4*)(Ds + off);
    *(uint4*)(Yb + (size_t)fl*8) = val;
  }
}

// ------- K5: out[b][q][j] = sum_i (y*gate)[i] * w_out[j][i] -------
__global__ __launch_bounds__(256) void k_final(
    const unsigned short* __restrict__ Y, const unsigned short* __restrict__ gate,
    const float* __restrict__ wout, float* __restrict__ out)
{
  __shared__ float wsh[64*68];
  __shared__ float tsh[4][64];
  const int tid = threadIdx.x, wv = tid >> 6, lane = tid & 63;
  for (int i = tid; i < 4096; i += 256) wsh[(i >> 6)*68 + (i & 63)] = wout[i];
  __syncthreads();
  float wr[64];
  #pragma unroll
  for (int i = 0; i < 64; i += 4){
    float4 t = *(const float4*)&wsh[lane*68 + i];
    wr[i]=t.x; wr[i+1]=t.y; wr[i+2]=t.z; wr[i+3]=t.w;
  }
  const int b  = blockIdx.x & 511;
  const int q0 = (blockIdx.x >> 9) * 64;
  const int hh = lane >> 3, cc = lane & 7;   // j = lane decomposition
  // Y3[h][bx][q][cl]: bx = b>>4, cl = (b&15)*8 + c
  const size_t ybase = (size_t)(b >> 4) * 768 * 128 + (size_t)(b & 15) * 8 + cc;
  for (int rr = 0; rr < 16; ++rr){
    int q = q0 + wv*16 + rr;
    float yv = bf2f(Y[(size_t)(hh*32) * 768 * 128 + ybase + (size_t)q*128]);
    float gv = bf2f(gate[((size_t)b*NRES + q)*64 + lane]);
    tsh[wv][lane] = yv * gv;
    float a = 0.f;
    #pragma unroll
    for (int i = 0; i < 64; i += 4){
      float4 tt = *(const float4*)&tsh[wv][i];
      a += tt.x*wr[i] + tt.y*wr[i+1] + tt.z*wr[i+2] + tt.w*wr[i+3];
    }
    out[((size_t)b*NRES + q)*64 + lane] = a;
  }
}

extern "C" void kernel_launch(void* const* d_in, const int* in_sizes, int n_in,
                              void* d_out, int out_size, void* d_ws, size_t ws_size,
                              hipStream_t stream) {
  (void)in_sizes; (void)n_in; (void)out_size; (void)ws_size;
  const float* act    = (const float*)d_in[0];
  const float* mask   = (const float*)d_in[1];
  const float* pair   = (const float*)d_in[2];
  const float* ascale = (const float*)d_in[3];
  const float* abias  = (const float*)d_in[4];
  const float* pscale = (const float*)d_in[5];
  const float* pbias  = (const float*)d_in[6];
  const float* wl     = (const float*)d_in[7];
  const float* vproj  = (const float*)d_in[8];
  const float* wgate  = (const float*)d_in[9];
  const float* wout   = (const float*)d_in[10];
  float* out = (float*)d_out;

  char* ws = (char*)d_ws;
  float*          mbias   = (float*)(ws);                                   // 3 KB
  unsigned short* WvT     = (unsigned short*)(ws + 4096);                   // 8 KB
  unsigned short* WgT     = (unsigned short*)(ws + 12288);                  // 8 KB
  unsigned short* weights = (unsigned short*)(ws + 24576);                  // 9.4 MB  [h][q][k]
  unsigned short* v       = (unsigned short*)(ws + 24576 + 9437184);        // 50.3 MB [h][bc][k]
  unsigned short* gate    = (unsigned short*)(ws + 24576 + 9437184 + 50331648);       // 50.3 MB [b][k][64]
  unsigned short* y       = (unsigned short*)(ws + 24576 + 9437184 + 2*50331648ull);  // 50.3 MB [h][bx][q][cl]

  k_maskbias<<<dim3(3), dim3(256), 0, stream>>>(mask, mbias);
  k_prep<<<dim3(16), dim3(256), 0, stream>>>(vproj, wgate, WvT, WgT);
  k_pair<<<dim3(768), dim3(256), 0, stream>>>(pair, pscale, pbias, wl, mbias, weights);
  k_act<<<dim3(6144), dim3(256), 0, stream>>>(act, ascale, abias, WvT, WgT, v, gate);
  k_wavg<<<dim3(1536), dim3(256), 0, stream>>>(v, weights, y);
  k_final<<<dim3(6144), dim3(256), 0, stream>>>(y, gate, wout, out);
}

// Round 6
// 451.544 us; speedup vs baseline: 1.8017x; 1.0522x over previous
//
#include <hip/hip_runtime.h>
#include <hip/hip_bf16.h>

#define NSEQ 512
#define NRES 768
#define MSAC 64
#define PAIRC 128
#define NHEAD 8

typedef __attribute__((ext_vector_type(8))) short short8_t;
typedef __attribute__((ext_vector_type(4))) float f32x4;

__device__ __forceinline__ float bf2f(unsigned short u){
  return __uint_as_float(((unsigned int)u) << 16);
}
__device__ __forceinline__ unsigned short f2bf(float f){
  unsigned int x = __float_as_uint(f);
  x += 0x7fffu + ((x >> 16) & 1u);   // RTNE
  return (unsigned short)(x >> 16);
}
// async global->LDS, 16B per lane; lds base must be wave-uniform (lane*16 implicit)
__device__ __forceinline__ void glds16(const void* g, void* l){
  __builtin_amdgcn_global_load_lds(
      (const __attribute__((address_space(1))) unsigned int*)g,
      (__attribute__((address_space(3))) unsigned int*)l, 16, 0, 0);
}

// ---------------- K0: mask -> additive bias per k ----------------
__global__ void k_maskbias(const float* __restrict__ mask, float* __restrict__ bias){
  int k = blockIdx.x * 256 + threadIdx.x;
  if (k >= NRES) return;
  float m = -1e30f;
  for (int b = 0; b < NSEQ; ++b) m = fmaxf(m, mask[(size_t)b * NRES + k]);
  bias[k] = 1e9f * (bf2f(f2bf(m)) - 1.0f);   // reference casts max to bf16 first
}

// ---------------- K0b: weight prep ----------------
// WvT[j][i] = vproj[i][j]; WgT[j][i] = wgate[j][i]; WoH/WoL = hi/lo bf16 split of wout
__global__ void k_prep(const float* __restrict__ vproj, const float* __restrict__ wgate,
                       const float* __restrict__ wout,
                       unsigned short* __restrict__ WvT, unsigned short* __restrict__ WgT,
                       unsigned short* __restrict__ WoH, unsigned short* __restrict__ WoL){
  int t = blockIdx.x * 256 + threadIdx.x;   // 4096 total
  if (t >= 4096) return;
  int j = t >> 6, i = t & 63;
  WvT[t] = f2bf(vproj[i * 64 + j]);
  WgT[t] = f2bf(wgate[t]);                  // w_gate[j][i] already row=out
  float wv = wout[t];
  unsigned short h = f2bf(wv);
  WoH[t] = h;
  WoL[t] = f2bf(wv - bf2f(h));
}

// ------- K1: pair LN + logits + softmax -> weights bf16 [h][q][k] -------
__global__ __launch_bounds__(256) void k_pair(
    const float* __restrict__ pair, const float* __restrict__ pscale,
    const float* __restrict__ pbias, const float* __restrict__ wl,
    const float* __restrict__ mbias, unsigned short* __restrict__ weights)
{
  __shared__ float lg[NHEAD][NRES];   // 24 KB
  const int q = blockIdx.x;
  const int tid = threadIdx.x;
  const int wv = tid >> 6, lane = tid & 63;
  const int g = lane & 7;
  const int c0 = g * 16;

  float scl[16], bsl[16];
  #pragma unroll
  for (int i = 0; i < 4; ++i){
    float4 s4 = *(const float4*)(pscale + c0 + i*4);
    float4 b4 = *(const float4*)(pbias  + c0 + i*4);
    scl[4*i+0]=s4.x; scl[4*i+1]=s4.y; scl[4*i+2]=s4.z; scl[4*i+3]=s4.w;
    bsl[4*i+0]=b4.x; bsl[4*i+1]=b4.y; bsl[4*i+2]=b4.z; bsl[4*i+3]=b4.w;
  }
  unsigned int wp[8][8];
  #pragma unroll
  for (int h = 0; h < 8; ++h){
    #pragma unroll
    for (int jj = 0; jj < 8; ++jj){
      float2 w2 = *(const float2*)(wl + h*PAIRC + c0 + jj*2);
      wp[h][jj] = (unsigned int)f2bf(w2.x) | ((unsigned int)f2bf(w2.y) << 16);
    }
  }

  for (int it = 0; it < 24; ++it){
    int k = it*32 + wv*8 + (lane >> 3);
    const float* prow = pair + ((size_t)q * NRES + k) * PAIRC + c0;
    float x[16];
    #pragma unroll
    for (int i = 0; i < 4; ++i){
      float4 v4 = *(const float4*)(prow + i*4);
      x[4*i+0]=v4.x; x[4*i+1]=v4.y; x[4*i+2]=v4.z; x[4*i+3]=v4.w;
    }
    float s = 0.f, ss = 0.f;
    #pragma unroll
    for (int i = 0; i < 16; ++i){ s += x[i]; ss += x[i]*x[i]; }
    #pragma unroll
    for (int m = 1; m < 8; m <<= 1){
      s  += __shfl_xor(s,  m, 64);
      ss += __shfl_xor(ss, m, 64);
    }
    float mu  = s * (1.f/128.f);
    float var = ss * (1.f/128.f) - mu*mu;
    float rs  = rsqrtf(var + 1e-5f);
    #pragma unroll
    for (int i = 0; i < 16; ++i) x[i] = (x[i] - mu) * rs * scl[i] + bsl[i];
    float ph[8];
    #pragma unroll
    for (int h = 0; h < 8; ++h){
      float p = 0.f;
      #pragma unroll
      for (int jj = 0; jj < 8; ++jj){
        unsigned int w = wp[h][jj];
        float wlo = __uint_as_float(w << 16);
        float whi = __uint_as_float(w & 0xffff0000u);
        p += x[2*jj] * wlo + x[2*jj+1] * whi;
      }
      ph[h] = p;
    }
    #pragma unroll
    for (int h = 0; h < 8; ++h){
      #pragma unroll
      for (int m = 1; m < 8; m <<= 1) ph[h] += __shfl_xor(ph[h], m, 64);
    }
    #pragma unroll
    for (int h = 0; h < 8; ++h) if (g == h) lg[h][k] = ph[h];
  }
  __syncthreads();
  #pragma unroll
  for (int hh = 0; hh < 2; ++hh){
    int h = wv + hh*4;
    float mx = -1e30f;
    for (int kk = lane; kk < NRES; kk += 64) mx = fmaxf(mx, lg[h][kk] + mbias[kk]);
    #pragma unroll
    for (int m = 1; m < 64; m <<= 1) mx = fmaxf(mx, __shfl_xor(mx, m, 64));
    float sum = 0.f;
    for (int kk = lane; kk < NRES; kk += 64){
      float e = __expf(lg[h][kk] + mbias[kk] - mx);
      lg[h][kk] = e; sum += e;
    }
    #pragma unroll
    for (int m = 1; m < 64; m <<= 1) sum += __shfl_xor(sum, m, 64);
    float inv = 1.0f / sum;
    unsigned short* wrow = weights + ((size_t)h * NRES + q) * NRES;
    for (int kk = lane; kk < NRES; kk += 64) wrow[kk] = f2bf(lg[h][kk] * inv);
  }
}

// ------- K3: act LN + v/gate via register-direct MFMA, LDS-staged stores -------
__global__ __launch_bounds__(256) void k_act(
    const float* __restrict__ act, const float* __restrict__ ascale,
    const float* __restrict__ abias, const unsigned short* __restrict__ WvT,
    const unsigned short* __restrict__ WgT, unsigned short* __restrict__ v,
    unsigned short* __restrict__ gate)
{
  __shared__ unsigned short vt[64][72];   // [j][k_local], padded (144B rows, 16B-aligned)
  __shared__ unsigned short gt[64][72];   // [k_local][j]
  const int b  = blockIdx.x / 12;
  const int k0 = (blockIdx.x % 12) * 64;
  const int tid = threadIdx.x, w = tid >> 6, lane = tid & 63;
  const int lr = lane & 15;          // A row within wave tile
  const int lc = lane >> 4;          // i-chunk selector (0..3)
  const int row = k0 + w*16 + lr;    // global k row this lane loads

  const float* arow = act + ((size_t)b*NRES + row)*MSAC;
  float x[2][8];
  #pragma unroll
  for (int s = 0; s < 2; ++s){
    float4 t0 = *(const float4*)(arow + s*32 + lc*8);
    float4 t1 = *(const float4*)(arow + s*32 + lc*8 + 4);
    x[s][0]=t0.x; x[s][1]=t0.y; x[s][2]=t0.z; x[s][3]=t0.w;
    x[s][4]=t1.x; x[s][5]=t1.y; x[s][6]=t1.z; x[s][7]=t1.w;
  }
  float ps = 0.f, pss = 0.f;
  #pragma unroll
  for (int s = 0; s < 2; ++s)
    #pragma unroll
    for (int e = 0; e < 8; ++e){ ps += x[s][e]; pss += x[s][e]*x[s][e]; }
  ps  += __shfl_xor(ps, 16, 64);  pss += __shfl_xor(pss, 16, 64);
  ps  += __shfl_xor(ps, 32, 64);  pss += __shfl_xor(pss, 32, 64);
  const float mu  = ps * (1.f/64.f);
  const float var = pss * (1.f/64.f) - mu*mu;
  const float rs  = rsqrtf(var + 1e-5f);

  short8_t a[2];
  #pragma unroll
  for (int s = 0; s < 2; ++s){
    float4 s0 = *(const float4*)(ascale + s*32 + lc*8);
    float4 s1 = *(const float4*)(ascale + s*32 + lc*8 + 4);
    float4 b0 = *(const float4*)(abias  + s*32 + lc*8);
    float4 b1 = *(const float4*)(abias  + s*32 + lc*8 + 4);
    const float sc[8] = {s0.x,s0.y,s0.z,s0.w,s1.x,s1.y,s1.z,s1.w};
    const float bs[8] = {b0.x,b0.y,b0.z,b0.w,b1.x,b1.y,b1.z,b1.w};
    #pragma unroll
    for (int e = 0; e < 8; ++e)
      a[s][e] = (short)f2bf((x[s][e] - mu)*rs*sc[e] + bs[e]);
  }

  short8_t bv[4][2], bg[4][2];
  #pragma unroll
  for (int mf = 0; mf < 4; ++mf){
    #pragma unroll
    for (int s = 0; s < 2; ++s){
      bv[mf][s] = *(const short8_t*)(WvT + (mf*16 + lr)*64 + s*32 + lc*8);
      bg[mf][s] = *(const short8_t*)(WgT + (mf*16 + lr)*64 + s*32 + lc*8);
    }
  }

  f32x4 accv[4], accg[4];
  #pragma unroll
  for (int mf = 0; mf < 4; ++mf){ accv[mf] = 0.f; accg[mf] = 0.f; }
  #pragma unroll
  for (int mf = 0; mf < 4; ++mf){
    #pragma unroll
    for (int s = 0; s < 2; ++s){
      accv[mf] = __builtin_amdgcn_mfma_f32_16x16x32_bf16(a[s], bv[mf][s], accv[mf], 0, 0, 0);
      accg[mf] = __builtin_amdgcn_mfma_f32_16x16x32_bf16(bg[mf][s], a[s], accg[mf], 0, 0, 0);
    }
  }

  // stage epilogues in LDS (full-line global stores afterwards)
  // accv: D row = k_local (w*16 + lc*4 + e), col = j (mf*16 + lr)  -> vt[j][k]
  // accg: D row = j (mf*16 + lc*4 + e),     col = k_local (w*16+lr) -> gt[k][j]
  #pragma unroll
  for (int mf = 0; mf < 4; ++mf){
    ushort4 ov;
    ov.x = f2bf(accv[mf][0]); ov.y = f2bf(accv[mf][1]);
    ov.z = f2bf(accv[mf][2]); ov.w = f2bf(accv[mf][3]);
    *(ushort4*)&vt[mf*16 + lr][w*16 + lc*4] = ov;
    ushort4 og;
    og.x = f2bf(1.0f/(1.0f + __expf(-accg[mf][0])));
    og.y = f2bf(1.0f/(1.0f + __expf(-accg[mf][1])));
    og.z = f2bf(1.0f/(1.0f + __expf(-accg[mf][2])));
    og.w = f2bf(1.0f/(1.0f + __expf(-accg[mf][3])));
    *(ushort4*)&gt[w*16 + lr][mf*16 + lc*4] = og;
  }
  __syncthreads();
  // v rows: j -> 128B contiguous at v[(h*4096+b*8+c)*768 + k0]
  #pragma unroll
  for (int it = 0; it < 2; ++it){
    int fl = it*256 + tid;
    int j = fl >> 3, chunk = fl & 7;
    uint4 val = *(const uint4*)&vt[j][chunk*8];
    *(uint4*)(v + ((size_t)(j >> 3)*4096 + (size_t)b*8 + (j & 7))*NRES + k0 + chunk*8) = val;
  }
  // gate rows: k -> 128B contiguous at gate[(b*768+k)*64]
  #pragma unroll
  for (int it = 0; it < 2; ++it){
    int fl = it*256 + tid;
    int k = fl >> 3, chunk = fl & 7;
    uint4 val = *(const uint4*)&gt[k][chunk*8];
    *(uint4*)(gate + ((size_t)b*NRES + k0 + k)*MSAC + chunk*8) = val;
  }
}

// ------- K4: per-head GEMM  Y3[h][bx][q][cl] = weights[h] @ v[h] -------
__global__ __launch_bounds__(256) void k_wavg(
    const unsigned short* __restrict__ V, const unsigned short* __restrict__ W,
    unsigned short* __restrict__ Y)
{
  __shared__ unsigned char smem[32768];
  unsigned char* As = smem;            // 16 KB [row 128][128B of k], swizzled
  unsigned char* Bs = smem + 16384;    // 16 KB

  const int flat = blockIdx.x;
  const int nid  = (flat & 7) * 192 + (flat >> 3);   // XCD chunk of 192 = 1 head
  const int m    = nid % 192;
  const int by   = m % 6;              // fastest: A-tile reuse across 6 blocks
  const int bx   = m / 6;
  const int h    = nid / 192;

  const int tid = threadIdx.x, wid = tid >> 6, lane = tid & 63;
  const int wm = wid & 1, wn = wid >> 1;
  const unsigned short* Ag = V + (size_t)h*4096*768 + (size_t)bx*128*768;
  const unsigned short* Bg = W + (size_t)h*768*768 + (size_t)by*128*768;

  f32x4 acc[4][4];
  #pragma unroll
  for (int i=0;i<4;++i){
    #pragma unroll
    for (int jj=0;jj<4;++jj) acc[i][jj] = 0.f;
  }

  const int srow0 = wid * 32;
  for (int kt = 0; kt < 12; ++kt){
    __syncthreads();
    #pragma unroll
    for (int r = 0; r < 4; ++r){
      int cid = (srow0 + r*8) * 8 + lane;
      int row = cid >> 3, ch = cid & 7;
      int sc = ch ^ (row & 7);
      glds16(Ag + (size_t)row*768 + kt*64 + sc*8, As + cid*16 - lane*16);
      glds16(Bg + (size_t)row*768 + kt*64 + sc*8, Bs + cid*16 - lane*16);
    }
    __syncthreads();
    #pragma unroll
    for (int kf = 0; kf < 2; ++kf){
      short8_t af[4], bf[4];
      const int kb = kf*64 + ((lane >> 4) << 4);
      #pragma unroll
      for (int mf = 0; mf < 4; ++mf){
        int row = wm*64 + mf*16 + (lane & 15);
        int off = row*128 + kb; off ^= (row & 7) << 4;
        af[mf] = *(const short8_t*)(As + off);
      }
      #pragma unroll
      for (int nf = 0; nf < 4; ++nf){
        int row = wn*64 + nf*16 + (lane & 15);
        int off = row*128 + kb; off ^= (row & 7) << 4;
        bf[nf] = *(const short8_t*)(Bs + off);
      }
      #pragma unroll
      for (int mf = 0; mf < 4; ++mf){
        #pragma unroll
        for (int nf = 0; nf < 4; ++nf)
          acc[mf][nf] = __builtin_amdgcn_mfma_f32_16x16x32_bf16(af[mf], bf[nf], acc[mf][nf], 0, 0, 0);
      }
    }
  }
  __syncthreads();
  unsigned char* Ds = smem;              // 32 KB: [q_local 128][bc_local 128] bf16
  #pragma unroll
  for (int mf = 0; mf < 4; ++mf){
    int bc = wm*64 + mf*16 + ((lane >> 4) << 2);
    #pragma unroll
    for (int nf = 0; nf < 4; ++nf){
      int q = wn*64 + nf*16 + (lane & 15);
      f32x4 a = acc[mf][nf];
      ushort4 o;
      o.x = f2bf(a[0]); o.y = f2bf(a[1]); o.z = f2bf(a[2]); o.w = f2bf(a[3]);
      int off = q*256 + bc*2; off ^= (q & 7) << 4;
      *(ushort4*)(Ds + off) = o;
    }
  }
  __syncthreads();
  unsigned short* Yb = Y + ((size_t)(h*32 + bx)*768 + by*128)*128;
  #pragma unroll
  for (int it = 0; it < 8; ++it){
    int fl = it*256 + tid;
    int q = fl >> 4, chunk = fl & 15;
    int off = q*256 + chunk*16; off ^= (q & 7) << 4;
    uint4 val = *(const uint4*)(Ds + off);
    *(uint4*)(Yb + (size_t)fl*8) = val;
  }
}

// ------- K5: out[b][q][:] = (y*gate) @ wout^T via MFMA (hi/lo split) -------
// grid: b fastest (Y 16B-chunk line sharing through L2). 64 q rows per block.
__global__ __launch_bounds__(256) void k_final(
    const unsigned short* __restrict__ Y, const unsigned short* __restrict__ gate,
    const unsigned short* __restrict__ WoH, const unsigned short* __restrict__ WoL,
    float* __restrict__ out)
{
  const int b  = blockIdx.x & 511;
  const int q0 = (blockIdx.x >> 9) * 64;
  const int tid = threadIdx.x, w = tid >> 6, lane = tid & 63;
  const int lr = lane & 15, lc = lane >> 4;

  // B fragments: wout rows j = nf*16+lr, i-chunk s*32+lc*8 (hi & lo planes)
  short8_t bh[4][2], bl[4][2];
  #pragma unroll
  for (int nf = 0; nf < 4; ++nf){
    #pragma unroll
    for (int s = 0; s < 2; ++s){
      bh[nf][s] = *(const short8_t*)(WoH + (nf*16 + lr)*64 + s*32 + lc*8);
      bl[nf][s] = *(const short8_t*)(WoL + (nf*16 + lr)*64 + s*32 + lc*8);
    }
  }

  // A fragments: yg row q = q0 + w*16 + lr, i = s*32 + lc*8 + e
  const int q = q0 + w*16 + lr;
  short8_t ah[2], al[2];
  #pragma unroll
  for (int s = 0; s < 2; ++s){
    const int hh = s*4 + lc;          // head = i>>3
    short8_t y8 = *(const short8_t*)(Y + ((size_t)(hh*32 + (b >> 4))*768 + q)*128 + (b & 15)*8);
    short8_t g8 = *(const short8_t*)(gate + ((size_t)b*NRES + q)*MSAC + s*32 + lc*8);
    #pragma unroll
    for (int e = 0; e < 8; ++e){
      float p = bf2f((unsigned short)y8[e]) * bf2f((unsigned short)g8[e]);
      unsigned short hi = f2bf(p);
      ah[s][e] = (short)hi;
      al[s][e] = (short)f2bf(p - bf2f(hi));
    }
  }

  f32x4 acc[4];
  #pragma unroll
  for (int nf = 0; nf < 4; ++nf) acc[nf] = 0.f;
  #pragma unroll
  for (int nf = 0; nf < 4; ++nf){
    #pragma unroll
    for (int s = 0; s < 2; ++s){
      acc[nf] = __builtin_amdgcn_mfma_f32_16x16x32_bf16(ah[s], bh[nf][s], acc[nf], 0, 0, 0);
      acc[nf] = __builtin_amdgcn_mfma_f32_16x16x32_bf16(al[s], bh[nf][s], acc[nf], 0, 0, 0);
      acc[nf] = __builtin_amdgcn_mfma_f32_16x16x32_bf16(ah[s], bl[nf][s], acc[nf], 0, 0, 0);
    }
  }

  // D: row = q_local lc*4+e (within wave tile), col = j nf*16+lr
  #pragma unroll
  for (int nf = 0; nf < 4; ++nf){
    #pragma unroll
    for (int e = 0; e < 4; ++e){
      int qq = q0 + w*16 + lc*4 + e;
      out[((size_t)b*NRES + qq)*MSAC + nf*16 + lr] = acc[nf][e];
    }
  }
}

extern "C" void kernel_launch(void* const* d_in, const int* in_sizes, int n_in,
                              void* d_out, int out_size, void* d_ws, size_t ws_size,
                              hipStream_t stream) {
  (void)in_sizes; (void)n_in; (void)out_size; (void)ws_size;
  const float* act    = (const float*)d_in[0];
  const float* mask   = (const float*)d_in[1];
  const float* pair   = (const float*)d_in[2];
  const float* ascale = (const float*)d_in[3];
  const float* abias  = (const float*)d_in[4];
  const float* pscale = (const float*)d_in[5];
  const float* pbias  = (const float*)d_in[6];
  const float* wl     = (const float*)d_in[7];
  const float* vproj  = (const float*)d_in[8];
  const float* wgate  = (const float*)d_in[9];
  const float* wout   = (const float*)d_in[10];
  float* out = (float*)d_out;

  char* ws = (char*)d_ws;
  float*          mbias   = (float*)(ws);                                   // 3 KB
  unsigned short* WvT     = (unsigned short*)(ws + 4096);                   // 8 KB
  unsigned short* WgT     = (unsigned short*)(ws + 12288);                  // 8 KB
  unsigned short* WoH     = (unsigned short*)(ws + 20480);                  // 8 KB
  unsigned short* WoL     = (unsigned short*)(ws + 28672);                  // 8 KB
  unsigned short* weights = (unsigned short*)(ws + 36864);                  // 9.4 MB  [h][q][k]
  unsigned short* v       = (unsigned short*)(ws + 36864 + 9437184);        // 50.3 MB [h][bc][k]
  unsigned short* gate    = (unsigned short*)(ws + 36864 + 9437184 + 50331648);       // 50.3 MB [b][k][64]
  unsigned short* y       = (unsigned short*)(ws + 36864 + 9437184 + 2*50331648ull);  // 50.3 MB [h][bx][q][cl]

  k_maskbias<<<dim3(3), dim3(256), 0, stream>>>(mask, mbias);
  k_prep<<<dim3(16), dim3(256), 0, stream>>>(vproj, wgate, wout, WvT, WgT, WoH, WoL);
  k_pair<<<dim3(768), dim3(256), 0, stream>>>(pair, pscale, pbias, wl, mbias, weights);
  k_act<<<dim3(6144), dim3(256), 0, stream>>>(act, ascale, abias, WvT, WgT, v, gate);
  k_wavg<<<dim3(1536), dim3(256), 0, stream>>>(v, weights, y);
  k_final<<<dim3(6144), dim3(256), 0, stream>>>(y, gate, WoH, WoL, out);
}

// Round 7
// 358.272 us; speedup vs baseline: 2.2707x; 1.2603x over previous
//
#include <hip/hip_runtime.h>
#include <hip/hip_bf16.h>

#define NSEQ 512
#define NRES 768
#define MSAC 64
#define PAIRC 128
#define NHEAD 8

typedef __attribute__((ext_vector_type(8))) short short8_t;
typedef __attribute__((ext_vector_type(4))) float f32x4;

__device__ __forceinline__ float bf2f(unsigned short u){
  return __uint_as_float(((unsigned int)u) << 16);
}
__device__ __forceinline__ unsigned short f2bf(float f){
  unsigned int x = __float_as_uint(f);
  x += 0x7fffu + ((x >> 16) & 1u);   // RTNE
  return (unsigned short)(x >> 16);
}
// async global->LDS, 16B per lane; lds base must be wave-uniform (lane*16 implicit)
__device__ __forceinline__ void glds16(const void* g, void* l){
  __builtin_amdgcn_global_load_lds(
      (const __attribute__((address_space(1))) unsigned int*)g,
      (__attribute__((address_space(3))) unsigned int*)l, 16, 0, 0);
}

// ---------------- K0: mask max (coalesced) + weight prep, merged ----------------
__global__ __launch_bounds__(256) void k_prep2(
    const float* __restrict__ mask, const float* __restrict__ vproj,
    const float* __restrict__ wgate, const float* __restrict__ wout,
    float* __restrict__ bias, unsigned short* __restrict__ WvT,
    unsigned short* __restrict__ WgT, unsigned short* __restrict__ WoH,
    unsigned short* __restrict__ WoL)
{
  const int bid = blockIdx.x, tid = threadIdx.x;
  if (bid < 12){
    __shared__ float red[4][64];
    const int kk = bid*64 + (tid & 63);
    const int bs = tid >> 6;
    float m = -1e30f;
    for (int b = bs; b < NSEQ; b += 4) m = fmaxf(m, mask[(size_t)b*NRES + kk]);
    red[bs][tid & 63] = m;
    __syncthreads();
    if (tid < 64){
      float mm = fmaxf(fmaxf(red[0][tid], red[1][tid]),
                       fmaxf(red[2][tid], red[3][tid]));
      bias[bid*64 + tid] = 1e9f * (bf2f(f2bf(mm)) - 1.0f);  // ref casts max to bf16
    }
  } else {
    const int t = (bid - 12)*256 + tid;   // 4096 total
    const int j = t >> 6, i = t & 63;
    WvT[t] = f2bf(vproj[i*64 + j]);
    WgT[t] = f2bf(wgate[t]);
    float wv = wout[t];
    unsigned short hh = f2bf(wv);
    WoH[t] = hh;
    WoL[t] = f2bf(wv - bf2f(hh));
  }
}

// ------- K1: pair LN + logits + softmax -> weights bf16 [h][q][k] -------
__global__ __launch_bounds__(256) void k_pair(
    const float* __restrict__ pair, const float* __restrict__ pscale,
    const float* __restrict__ pbias, const float* __restrict__ wl,
    const float* __restrict__ mbias, unsigned short* __restrict__ weights)
{
  __shared__ float lg[NHEAD][NRES];   // 24 KB
  const int q = blockIdx.x;
  const int tid = threadIdx.x;
  const int wv = tid >> 6, lane = tid & 63;
  const int g = lane & 7;
  const int c0 = g * 16;

  float scl[16], bsl[16];
  #pragma unroll
  for (int i = 0; i < 4; ++i){
    float4 s4 = *(const float4*)(pscale + c0 + i*4);
    float4 b4 = *(const float4*)(pbias  + c0 + i*4);
    scl[4*i+0]=s4.x; scl[4*i+1]=s4.y; scl[4*i+2]=s4.z; scl[4*i+3]=s4.w;
    bsl[4*i+0]=b4.x; bsl[4*i+1]=b4.y; bsl[4*i+2]=b4.z; bsl[4*i+3]=b4.w;
  }
  unsigned int wp[8][8];
  #pragma unroll
  for (int h = 0; h < 8; ++h){
    #pragma unroll
    for (int jj = 0; jj < 8; ++jj){
      float2 w2 = *(const float2*)(wl + h*PAIRC + c0 + jj*2);
      wp[h][jj] = (unsigned int)f2bf(w2.x) | ((unsigned int)f2bf(w2.y) << 16);
    }
  }

  for (int it = 0; it < 24; ++it){
    int k = it*32 + wv*8 + (lane >> 3);
    const float* prow = pair + ((size_t)q * NRES + k) * PAIRC + c0;
    float x[16];
    #pragma unroll
    for (int i = 0; i < 4; ++i){
      float4 v4 = *(const float4*)(prow + i*4);
      x[4*i+0]=v4.x; x[4*i+1]=v4.y; x[4*i+2]=v4.z; x[4*i+3]=v4.w;
    }
    float s = 0.f, ss = 0.f;
    #pragma unroll
    for (int i = 0; i < 16; ++i){ s += x[i]; ss += x[i]*x[i]; }
    #pragma unroll
    for (int m = 1; m < 8; m <<= 1){
      s  += __shfl_xor(s,  m, 64);
      ss += __shfl_xor(ss, m, 64);
    }
    float mu  = s * (1.f/128.f);
    float var = ss * (1.f/128.f) - mu*mu;
    float rs  = rsqrtf(var + 1e-5f);
    #pragma unroll
    for (int i = 0; i < 16; ++i) x[i] = (x[i] - mu) * rs * scl[i] + bsl[i];
    float ph[8];
    #pragma unroll
    for (int h = 0; h < 8; ++h){
      float p = 0.f;
      #pragma unroll
      for (int jj = 0; jj < 8; ++jj){
        unsigned int w = wp[h][jj];
        float wlo = __uint_as_float(w << 16);
        float whi = __uint_as_float(w & 0xffff0000u);
        p += x[2*jj] * wlo + x[2*jj+1] * whi;
      }
      ph[h] = p;
    }
    #pragma unroll
    for (int h = 0; h < 8; ++h){
      #pragma unroll
      for (int m = 1; m < 8; m <<= 1) ph[h] += __shfl_xor(ph[h], m, 64);
    }
    #pragma unroll
    for (int h = 0; h < 8; ++h) if (g == h) lg[h][k] = ph[h];
  }
  __syncthreads();
  #pragma unroll
  for (int hh = 0; hh < 2; ++hh){
    int h = wv + hh*4;
    float mx = -1e30f;
    for (int kk = lane; kk < NRES; kk += 64) mx = fmaxf(mx, lg[h][kk] + mbias[kk]);
    #pragma unroll
    for (int m = 1; m < 64; m <<= 1) mx = fmaxf(mx, __shfl_xor(mx, m, 64));
    float sum = 0.f;
    for (int kk = lane; kk < NRES; kk += 64){
      float e = __expf(lg[h][kk] + mbias[kk] - mx);
      lg[h][kk] = e; sum += e;
    }
    #pragma unroll
    for (int m = 1; m < 64; m <<= 1) sum += __shfl_xor(sum, m, 64);
    float inv = 1.0f / sum;
    unsigned short* wrow = weights + ((size_t)h * NRES + q) * NRES;
    for (int kk = lane; kk < NRES; kk += 64) wrow[kk] = f2bf(lg[h][kk] * inv);
  }
}

// ------- K3: act LN + v/gate via register-direct MFMA, LDS-staged stores -------
__global__ __launch_bounds__(256) void k_act(
    const float* __restrict__ act, const float* __restrict__ ascale,
    const float* __restrict__ abias, const unsigned short* __restrict__ WvT,
    const unsigned short* __restrict__ WgT, unsigned short* __restrict__ v,
    unsigned short* __restrict__ gate)
{
  __shared__ unsigned short vt[64][72];   // [j][k_local], padded
  __shared__ unsigned short gt[64][72];   // [k_local][j]
  const int b  = blockIdx.x / 12;
  const int k0 = (blockIdx.x % 12) * 64;
  const int tid = threadIdx.x, w = tid >> 6, lane = tid & 63;
  const int lr = lane & 15;          // A row within wave tile
  const int lc = lane >> 4;          // i-chunk selector (0..3)
  const int row = k0 + w*16 + lr;    // global k row this lane loads

  const float* arow = act + ((size_t)b*NRES + row)*MSAC;
  float x[2][8];
  #pragma unroll
  for (int s = 0; s < 2; ++s){
    float4 t0 = *(const float4*)(arow + s*32 + lc*8);
    float4 t1 = *(const float4*)(arow + s*32 + lc*8 + 4);
    x[s][0]=t0.x; x[s][1]=t0.y; x[s][2]=t0.z; x[s][3]=t0.w;
    x[s][4]=t1.x; x[s][5]=t1.y; x[s][6]=t1.z; x[s][7]=t1.w;
  }
  float ps = 0.f, pss = 0.f;
  #pragma unroll
  for (int s = 0; s < 2; ++s)
    #pragma unroll
    for (int e = 0; e < 8; ++e){ ps += x[s][e]; pss += x[s][e]*x[s][e]; }
  ps  += __shfl_xor(ps, 16, 64);  pss += __shfl_xor(pss, 16, 64);
  ps  += __shfl_xor(ps, 32, 64);  pss += __shfl_xor(pss, 32, 64);
  const float mu  = ps * (1.f/64.f);
  const float var = pss * (1.f/64.f) - mu*mu;
  const float rs  = rsqrtf(var + 1e-5f);

  short8_t a[2];
  #pragma unroll
  for (int s = 0; s < 2; ++s){
    float4 s0 = *(const float4*)(ascale + s*32 + lc*8);
    float4 s1 = *(const float4*)(ascale + s*32 + lc*8 + 4);
    float4 b0 = *(const float4*)(abias  + s*32 + lc*8);
    float4 b1 = *(const float4*)(abias  + s*32 + lc*8 + 4);
    const float sc[8] = {s0.x,s0.y,s0.z,s0.w,s1.x,s1.y,s1.z,s1.w};
    const float bs[8] = {b0.x,b0.y,b0.z,b0.w,b1.x,b1.y,b1.z,b1.w};
    #pragma unroll
    for (int e = 0; e < 8; ++e)
      a[s][e] = (short)f2bf((x[s][e] - mu)*rs*sc[e] + bs[e]);
  }

  short8_t bv[4][2], bg[4][2];
  #pragma unroll
  for (int mf = 0; mf < 4; ++mf){
    #pragma unroll
    for (int s = 0; s < 2; ++s){
      bv[mf][s] = *(const short8_t*)(WvT + (mf*16 + lr)*64 + s*32 + lc*8);
      bg[mf][s] = *(const short8_t*)(WgT + (mf*16 + lr)*64 + s*32 + lc*8);
    }
  }

  f32x4 accv[4], accg[4];
  #pragma unroll
  for (int mf = 0; mf < 4; ++mf){ accv[mf] = 0.f; accg[mf] = 0.f; }
  #pragma unroll
  for (int mf = 0; mf < 4; ++mf){
    #pragma unroll
    for (int s = 0; s < 2; ++s){
      accv[mf] = __builtin_amdgcn_mfma_f32_16x16x32_bf16(a[s], bv[mf][s], accv[mf], 0, 0, 0);
      accg[mf] = __builtin_amdgcn_mfma_f32_16x16x32_bf16(bg[mf][s], a[s], accg[mf], 0, 0, 0);
    }
  }

  // stage epilogues in LDS (full-line global stores afterwards)
  #pragma unroll
  for (int mf = 0; mf < 4; ++mf){
    ushort4 ov;
    ov.x = f2bf(accv[mf][0]); ov.y = f2bf(accv[mf][1]);
    ov.z = f2bf(accv[mf][2]); ov.w = f2bf(accv[mf][3]);
    *(ushort4*)&vt[mf*16 + lr][w*16 + lc*4] = ov;
    ushort4 og;
    og.x = f2bf(1.0f/(1.0f + __expf(-accg[mf][0])));
    og.y = f2bf(1.0f/(1.0f + __expf(-accg[mf][1])));
    og.z = f2bf(1.0f/(1.0f + __expf(-accg[mf][2])));
    og.w = f2bf(1.0f/(1.0f + __expf(-accg[mf][3])));
    *(ushort4*)&gt[w*16 + lr][mf*16 + lc*4] = og;
  }
  __syncthreads();
  #pragma unroll
  for (int it = 0; it < 2; ++it){
    int fl = it*256 + tid;
    int j = fl >> 3, chunk = fl & 7;
    uint4 val = *(const uint4*)&vt[j][chunk*8];
    *(uint4*)(v + ((size_t)(j >> 3)*4096 + (size_t)b*8 + (j & 7))*NRES + k0 + chunk*8) = val;
  }
  #pragma unroll
  for (int it = 0; it < 2; ++it){
    int fl = it*256 + tid;
    int k = fl >> 3, chunk = fl & 7;
    uint4 val = *(const uint4*)&gt[k][chunk*8];
    *(uint4*)(gate + ((size_t)b*NRES + k0 + k)*MSAC + chunk*8) = val;
  }
}

// ------- K4: per-head GEMM  Y3[h][bx][q][cl] = weights[h] @ v[h] -------
// 2-phase double-buffered pipeline, BK=32: issue next-tile global_load_lds BEFORE
// compute, single __syncthreads() per K-step (= the vmcnt drain). 32 KB LDS total
// (2 bufs x (A 8K + B 8K)) -> 5 blocks/CU. Swizzle: 64B rows, 4 chunks, XOR
// (row>>1)&3 both sides (<=2-way banks, free).
__global__ __launch_bounds__(256) void k_wavg(
    const unsigned short* __restrict__ V, const unsigned short* __restrict__ W,
    unsigned short* __restrict__ Y)
{
  __shared__ unsigned char smem[32768];

  const int flat = blockIdx.x;
  const int nid  = (flat & 7) * 192 + (flat >> 3);   // XCD chunk of 192 = 1 head
  const int m    = nid % 192;
  const int by   = m % 6;              // fastest: A-tile reuse across 6 blocks
  const int bx   = m / 6;
  const int h    = nid / 192;

  const int tid = threadIdx.x, wid = tid >> 6, lane = tid & 63;
  const int wm = wid & 1, wn = wid >> 1;
  const unsigned short* Ag = V + (size_t)h*4096*768 + (size_t)bx*128*768;
  const unsigned short* Bg = W + (size_t)h*768*768 + (size_t)by*128*768;

  f32x4 acc[4][4];
  #pragma unroll
  for (int i=0;i<4;++i){
    #pragma unroll
    for (int jj=0;jj<4;++jj) acc[i][jj] = 0.f;
  }

  // STAGE(buf, kt): 128 rows x 64B per operand. cid = tid + r*256 (r<2):
  // row = cid>>2, ch = cid&3, source chunk = ch ^ ((row>>1)&3).
  // LDS dest linear at cid*16 (wave-uniform base + implicit lane*16).
  #define STAGE_K(bufsel, kt) { \
    unsigned char* Ab = smem + (bufsel)*16384; \
    unsigned char* Bb = Ab + 8192; \
    _Pragma("unroll") \
    for (int r = 0; r < 2; ++r){ \
      int cid = tid + r*256; \
      int rw = cid >> 2, ch = cid & 3; \
      int sc = ch ^ ((rw >> 1) & 3); \
      glds16(Ag + (size_t)rw*768 + (kt)*32 + sc*8, Ab + cid*16 - lane*16); \
      glds16(Bg + (size_t)rw*768 + (kt)*32 + sc*8, Bb + cid*16 - lane*16); \
    } }

  STAGE_K(0, 0);
  __syncthreads();
  const int c0 = lane >> 4;            // k-chunk selector
  for (int kt = 0; kt < 24; ++kt){
    if (kt < 23) STAGE_K((kt+1)&1, kt+1);     // prefetch overlaps compute below
    unsigned char* Ab = smem + (kt&1)*16384;
    unsigned char* Bb = Ab + 8192;
    short8_t af[4], bf[4];
    #pragma unroll
    for (int mf = 0; mf < 4; ++mf){
      int row = wm*64 + mf*16 + (lane & 15);
      int off = row*64 + ((c0 ^ ((row>>1)&3)) << 4);
      af[mf] = *(const short8_t*)(Ab + off);
    }
    #pragma unroll
    for (int nf = 0; nf < 4; ++nf){
      int row = wn*64 + nf*16 + (lane & 15);
      int off = row*64 + ((c0 ^ ((row>>1)&3)) << 4);
      bf[nf] = *(const short8_t*)(Bb + off);
    }
    #pragma unroll
    for (int mf = 0; mf < 4; ++mf){
      #pragma unroll
      for (int nf = 0; nf < 4; ++nf)
        acc[mf][nf] = __builtin_amdgcn_mfma_f32_16x16x32_bf16(af[mf], bf[nf], acc[mf][nf], 0, 0, 0);
    }
    __syncthreads();   // single drain: staged loads done + all reads of this buf done
  }
  #undef STAGE_K

  // ---- epilogue: D -> swizzled LDS (aliases bufs) -> contiguous 32 KB store ----
  unsigned char* Ds = smem;              // 32 KB: [q_local 128][bc_local 128] bf16
  #pragma unroll
  for (int mf = 0; mf < 4; ++mf){
    int bc = wm*64 + mf*16 + ((lane >> 4) << 2);
    #pragma unroll
    for (int nf = 0; nf < 4; ++nf){
      int q = wn*64 + nf*16 + (lane & 15);
      f32x4 a = acc[mf][nf];
      ushort4 o;
      o.x = f2bf(a[0]); o.y = f2bf(a[1]); o.z = f2bf(a[2]); o.w = f2bf(a[3]);
      int off = q*256 + bc*2; off ^= (q & 7) << 4;
      *(ushort4*)(Ds + off) = o;
    }
  }
  __syncthreads();
  unsigned short* Yb = Y + ((size_t)(h*32 + bx)*768 + by*128)*128;
  #pragma unroll
  for (int it = 0; it < 8; ++it){
    int fl = it*256 + tid;
    int q = fl >> 4, chunk = fl & 15;
    int off = q*256 + chunk*16; off ^= (q & 7) << 4;
    uint4 val = *(const uint4*)(Ds + off);
    *(uint4*)(Yb + (size_t)fl*8) = val;
  }
}

// ------- K5: out[b][q][:] = (y*gate) @ wout^T via MFMA (hi/lo split) -------
__global__ __launch_bounds__(256) void k_final(
    const unsigned short* __restrict__ Y, const unsigned short* __restrict__ gate,
    const unsigned short* __restrict__ WoH, const unsigned short* __restrict__ WoL,
    float* __restrict__ out)
{
  const int b  = blockIdx.x & 511;
  const int q0 = (blockIdx.x >> 9) * 64;
  const int tid = threadIdx.x, w = tid >> 6, lane = tid & 63;
  const int lr = lane & 15, lc = lane >> 4;

  short8_t bh[4][2], bl[4][2];
  #pragma unroll
  for (int nf = 0; nf < 4; ++nf){
    #pragma unroll
    for (int s = 0; s < 2; ++s){
      bh[nf][s] = *(const short8_t*)(WoH + (nf*16 + lr)*64 + s*32 + lc*8);
      bl[nf][s] = *(const short8_t*)(WoL + (nf*16 + lr)*64 + s*32 + lc*8);
    }
  }

  const int q = q0 + w*16 + lr;
  short8_t ah[2], al[2];
  #pragma unroll
  for (int s = 0; s < 2; ++s){
    const int hh = s*4 + lc;          // head = i>>3
    short8_t y8 = *(const short8_t*)(Y + ((size_t)(hh*32 + (b >> 4))*768 + q)*128 + (b & 15)*8);
    short8_t g8 = *(const short8_t*)(gate + ((size_t)b*NRES + q)*MSAC + s*32 + lc*8);
    #pragma unroll
    for (int e = 0; e < 8; ++e){
      float p = bf2f((unsigned short)y8[e]) * bf2f((unsigned short)g8[e]);
      unsigned short hi = f2bf(p);
      ah[s][e] = (short)hi;
      al[s][e] = (short)f2bf(p - bf2f(hi));
    }
  }

  f32x4 acc[4];
  #pragma unroll
  for (int nf = 0; nf < 4; ++nf) acc[nf] = 0.f;
  #pragma unroll
  for (int nf = 0; nf < 4; ++nf){
    #pragma unroll
    for (int s = 0; s < 2; ++s){
      acc[nf] = __builtin_amdgcn_mfma_f32_16x16x32_bf16(ah[s], bh[nf][s], acc[nf], 0, 0, 0);
      acc[nf] = __builtin_amdgcn_mfma_f32_16x16x32_bf16(al[s], bh[nf][s], acc[nf], 0, 0, 0);
      acc[nf] = __builtin_amdgcn_mfma_f32_16x16x32_bf16(ah[s], bl[nf][s], acc[nf], 0, 0, 0);
    }
  }

  #pragma unroll
  for (int nf = 0; nf < 4; ++nf){
    #pragma unroll
    for (int e = 0; e < 4; ++e){
      int qq = q0 + w*16 + lc*4 + e;
      out[((size_t)b*NRES + qq)*MSAC + nf*16 + lr] = acc[nf][e];
    }
  }
}

extern "C" void kernel_launch(void* const* d_in, const int* in_sizes, int n_in,
                              void* d_out, int out_size, void* d_ws, size_t ws_size,
                              hipStream_t stream) {
  (void)in_sizes; (void)n_in; (void)out_size; (void)ws_size;
  const float* act    = (const float*)d_in[0];
  const float* mask   = (const float*)d_in[1];
  const float* pair   = (const float*)d_in[2];
  const float* ascale = (const float*)d_in[3];
  const float* abias  = (const float*)d_in[4];
  const float* pscale = (const float*)d_in[5];
  const float* pbias  = (const float*)d_in[6];
  const float* wl     = (const float*)d_in[7];
  const float* vproj  = (const float*)d_in[8];
  const float* wgate  = (const float*)d_in[9];
  const float* wout   = (const float*)d_in[10];
  float* out = (float*)d_out;

  char* ws = (char*)d_ws;
  float*          mbias   = (float*)(ws);                                   // 3 KB
  unsigned short* WvT     = (unsigned short*)(ws + 4096);                   // 8 KB
  unsigned short* WgT     = (unsigned short*)(ws + 12288);                  // 8 KB
  unsigned short* WoH     = (unsigned short*)(ws + 20480);                  // 8 KB
  unsigned short* WoL     = (unsigned short*)(ws + 28672);                  // 8 KB
  unsigned short* weights = (unsigned short*)(ws + 36864);                  // 9.4 MB  [h][q][k]
  unsigned short* v       = (unsigned short*)(ws + 36864 + 9437184);        // 50.3 MB [h][bc][k]
  unsigned short* gate    = (unsigned short*)(ws + 36864 + 9437184 + 50331648);       // 50.3 MB [b][k][64]
  unsigned short* y       = (unsigned short*)(ws + 36864 + 9437184 + 2*50331648ull);  // 50.3 MB [h][bx][q][cl]

  k_prep2<<<dim3(28), dim3(256), 0, stream>>>(mask, vproj, wgate, wout,
                                              mbias, WvT, WgT, WoH, WoL);
  k_pair<<<dim3(768), dim3(256), 0, stream>>>(pair, pscale, pbias, wl, mbias, weights);
  k_act<<<dim3(6144), dim3(256), 0, stream>>>(act, ascale, abias, WvT, WgT, v, gate);
  k_wavg<<<dim3(1536), dim3(256), 0, stream>>>(v, weights, y);
  k_final<<<dim3(6144), dim3(256), 0, stream>>>(y, gate, WoH, WoL, out);
}

// Round 8
// 331.265 us; speedup vs baseline: 2.4558x; 1.0815x over previous
//
#include <hip/hip_runtime.h>
#include <hip/hip_bf16.h>

#define NSEQ 512
#define NRES 768
#define MSAC 64
#define PAIRC 128
#define NHEAD 8

typedef __attribute__((ext_vector_type(8))) short short8_t;
typedef __attribute__((ext_vector_type(4))) float f32x4;

__device__ __forceinline__ float bf2f(unsigned short u){
  return __uint_as_float(((unsigned int)u) << 16);
}
__device__ __forceinline__ unsigned short f2bf(float f){
  unsigned int x = __float_as_uint(f);
  x += 0x7fffu + ((x >> 16) & 1u);   // RTNE
  return (unsigned short)(x >> 16);
}
// async global->LDS, 16B per lane; lds base must be wave-uniform (lane*16 implicit)
__device__ __forceinline__ void glds16(const void* g, void* l){
  __builtin_amdgcn_global_load_lds(
      (const __attribute__((address_space(1))) unsigned int*)g,
      (__attribute__((address_space(3))) unsigned int*)l, 16, 0, 0);
}

// ---------------- K0: mask max (coalesced) + weight prep, merged ----------------
__global__ __launch_bounds__(256) void k_prep2(
    const float* __restrict__ mask, const float* __restrict__ vproj,
    const float* __restrict__ wgate, const float* __restrict__ wout,
    float* __restrict__ bias, unsigned short* __restrict__ WvT,
    unsigned short* __restrict__ WgT, unsigned short* __restrict__ WoH,
    unsigned short* __restrict__ WoL)
{
  const int bid = blockIdx.x, tid = threadIdx.x;
  if (bid < 12){
    __shared__ float red[4][64];
    const int kk = bid*64 + (tid & 63);
    const int bs = tid >> 6;
    float m = -1e30f;
    for (int b = bs; b < NSEQ; b += 4) m = fmaxf(m, mask[(size_t)b*NRES + kk]);
    red[bs][tid & 63] = m;
    __syncthreads();
    if (tid < 64){
      float mm = fmaxf(fmaxf(red[0][tid], red[1][tid]),
                       fmaxf(red[2][tid], red[3][tid]));
      bias[bid*64 + tid] = 1e9f * (bf2f(f2bf(mm)) - 1.0f);  // ref casts max to bf16
    }
  } else {
    const int t = (bid - 12)*256 + tid;   // 4096 total
    const int j = t >> 6, i = t & 63;
    WvT[t] = f2bf(vproj[i*64 + j]);
    WgT[t] = f2bf(wgate[t]);
    float wv = wout[t];
    unsigned short hh = f2bf(wv);
    WoH[t] = hh;
    WoL[t] = f2bf(wv - bf2f(hh));
  }
}

// ------- K1: merged pair-path + act-path (independent work, co-scheduled) -------
// bid < 768: pair LN + logits + softmax -> weights bf16 [h][q][k]   (q = bid)
// bid >= 768: act LN + v/gate via register-direct MFMA              (abid = bid-768)
__global__ __launch_bounds__(256) void k_pairact(
    const float* __restrict__ pair, const float* __restrict__ pscale,
    const float* __restrict__ pbias, const float* __restrict__ wl,
    const float* __restrict__ mbias, unsigned short* __restrict__ weights,
    const float* __restrict__ act, const float* __restrict__ ascale,
    const float* __restrict__ abias, const unsigned short* __restrict__ WvT,
    const unsigned short* __restrict__ WgT, unsigned short* __restrict__ v,
    unsigned short* __restrict__ gate)
{
  __shared__ __align__(16) unsigned char sm[24576];   // union: lg[8][768] f32 | vt+gt
  const int bid = blockIdx.x;
  const int tid = threadIdx.x;

  if (bid < 768){
    // =================== pair role ===================
    float (*lg)[NRES] = (float (*)[NRES])sm;   // 24 KB
    const int q = bid;
    const int wv = tid >> 6, lane = tid & 63;
    const int g = lane & 7;
    const int c0 = g * 16;

    float scl[16], bsl[16];
    #pragma unroll
    for (int i = 0; i < 4; ++i){
      float4 s4 = *(const float4*)(pscale + c0 + i*4);
      float4 b4 = *(const float4*)(pbias  + c0 + i*4);
      scl[4*i+0]=s4.x; scl[4*i+1]=s4.y; scl[4*i+2]=s4.z; scl[4*i+3]=s4.w;
      bsl[4*i+0]=b4.x; bsl[4*i+1]=b4.y; bsl[4*i+2]=b4.z; bsl[4*i+3]=b4.w;
    }
    unsigned int wp[8][8];
    #pragma unroll
    for (int h = 0; h < 8; ++h){
      #pragma unroll
      for (int jj = 0; jj < 8; ++jj){
        float2 w2 = *(const float2*)(wl + h*PAIRC + c0 + jj*2);
        wp[h][jj] = (unsigned int)f2bf(w2.x) | ((unsigned int)f2bf(w2.y) << 16);
      }
    }

    for (int it = 0; it < 24; ++it){
      int k = it*32 + wv*8 + (lane >> 3);
      const float* prow = pair + ((size_t)q * NRES + k) * PAIRC + c0;
      float x[16];
      #pragma unroll
      for (int i = 0; i < 4; ++i){
        float4 v4 = *(const float4*)(prow + i*4);
        x[4*i+0]=v4.x; x[4*i+1]=v4.y; x[4*i+2]=v4.z; x[4*i+3]=v4.w;
      }
      float s = 0.f, ss = 0.f;
      #pragma unroll
      for (int i = 0; i < 16; ++i){ s += x[i]; ss += x[i]*x[i]; }
      #pragma unroll
      for (int m = 1; m < 8; m <<= 1){
        s  += __shfl_xor(s,  m, 64);
        ss += __shfl_xor(ss, m, 64);
      }
      float mu  = s * (1.f/128.f);
      float var = ss * (1.f/128.f) - mu*mu;
      float rs  = rsqrtf(var + 1e-5f);
      #pragma unroll
      for (int i = 0; i < 16; ++i) x[i] = (x[i] - mu) * rs * scl[i] + bsl[i];
      float ph[8];
      #pragma unroll
      for (int h = 0; h < 8; ++h){
        float p = 0.f;
        #pragma unroll
        for (int jj = 0; jj < 8; ++jj){
          unsigned int w = wp[h][jj];
          float wlo = __uint_as_float(w << 16);
          float whi = __uint_as_float(w & 0xffff0000u);
          p += x[2*jj] * wlo + x[2*jj+1] * whi;
        }
        ph[h] = p;
      }
      #pragma unroll
      for (int h = 0; h < 8; ++h){
        #pragma unroll
        for (int m = 1; m < 8; m <<= 1) ph[h] += __shfl_xor(ph[h], m, 64);
      }
      #pragma unroll
      for (int h = 0; h < 8; ++h) if (g == h) lg[h][k] = ph[h];
    }
    __syncthreads();
    #pragma unroll
    for (int hh = 0; hh < 2; ++hh){
      int h = wv + hh*4;
      float mx = -1e30f;
      for (int kk = lane; kk < NRES; kk += 64) mx = fmaxf(mx, lg[h][kk] + mbias[kk]);
      #pragma unroll
      for (int m = 1; m < 64; m <<= 1) mx = fmaxf(mx, __shfl_xor(mx, m, 64));
      float sum = 0.f;
      for (int kk = lane; kk < NRES; kk += 64){
        float e = __expf(lg[h][kk] + mbias[kk] - mx);
        lg[h][kk] = e; sum += e;
      }
      #pragma unroll
      for (int m = 1; m < 64; m <<= 1) sum += __shfl_xor(sum, m, 64);
      float inv = 1.0f / sum;
      unsigned short* wrow = weights + ((size_t)h * NRES + q) * NRES;
      for (int kk = lane; kk < NRES; kk += 64) wrow[kk] = f2bf(lg[h][kk] * inv);
    }
  } else {
    // =================== act role ===================
    unsigned short (*vt)[72] = (unsigned short (*)[72])sm;            // 9216 B
    unsigned short (*gt)[72] = (unsigned short (*)[72])(sm + 9216);   // 9216 B
    const int abid = bid - 768;
    const int b  = abid / 12;
    const int k0 = (abid % 12) * 64;
    const int w = tid >> 6, lane = tid & 63;
    const int lr = lane & 15;
    const int lc = lane >> 4;
    const int row = k0 + w*16 + lr;

    const float* arow = act + ((size_t)b*NRES + row)*MSAC;
    float x[2][8];
    #pragma unroll
    for (int s = 0; s < 2; ++s){
      float4 t0 = *(const float4*)(arow + s*32 + lc*8);
      float4 t1 = *(const float4*)(arow + s*32 + lc*8 + 4);
      x[s][0]=t0.x; x[s][1]=t0.y; x[s][2]=t0.z; x[s][3]=t0.w;
      x[s][4]=t1.x; x[s][5]=t1.y; x[s][6]=t1.z; x[s][7]=t1.w;
    }
    float ps = 0.f, pss = 0.f;
    #pragma unroll
    for (int s = 0; s < 2; ++s)
      #pragma unroll
      for (int e = 0; e < 8; ++e){ ps += x[s][e]; pss += x[s][e]*x[s][e]; }
    ps  += __shfl_xor(ps, 16, 64);  pss += __shfl_xor(pss, 16, 64);
    ps  += __shfl_xor(ps, 32, 64);  pss += __shfl_xor(pss, 32, 64);
    const float mu  = ps * (1.f/64.f);
    const float var = pss * (1.f/64.f) - mu*mu;
    const float rs  = rsqrtf(var + 1e-5f);

    short8_t a[2];
    #pragma unroll
    for (int s = 0; s < 2; ++s){
      float4 s0 = *(const float4*)(ascale + s*32 + lc*8);
      float4 s1 = *(const float4*)(ascale + s*32 + lc*8 + 4);
      float4 b0 = *(const float4*)(abias  + s*32 + lc*8);
      float4 b1 = *(const float4*)(abias  + s*32 + lc*8 + 4);
      const float sc[8] = {s0.x,s0.y,s0.z,s0.w,s1.x,s1.y,s1.z,s1.w};
      const float bs[8] = {b0.x,b0.y,b0.z,b0.w,b1.x,b1.y,b1.z,b1.w};
      #pragma unroll
      for (int e = 0; e < 8; ++e)
        a[s][e] = (short)f2bf((x[s][e] - mu)*rs*sc[e] + bs[e]);
    }

    short8_t bv[4][2], bg[4][2];
    #pragma unroll
    for (int mf = 0; mf < 4; ++mf){
      #pragma unroll
      for (int s = 0; s < 2; ++s){
        bv[mf][s] = *(const short8_t*)(WvT + (mf*16 + lr)*64 + s*32 + lc*8);
        bg[mf][s] = *(const short8_t*)(WgT + (mf*16 + lr)*64 + s*32 + lc*8);
      }
    }

    f32x4 accv[4], accg[4];
    #pragma unroll
    for (int mf = 0; mf < 4; ++mf){ accv[mf] = 0.f; accg[mf] = 0.f; }
    #pragma unroll
    for (int mf = 0; mf < 4; ++mf){
      #pragma unroll
      for (int s = 0; s < 2; ++s){
        accv[mf] = __builtin_amdgcn_mfma_f32_16x16x32_bf16(a[s], bv[mf][s], accv[mf], 0, 0, 0);
        accg[mf] = __builtin_amdgcn_mfma_f32_16x16x32_bf16(bg[mf][s], a[s], accg[mf], 0, 0, 0);
      }
    }

    #pragma unroll
    for (int mf = 0; mf < 4; ++mf){
      ushort4 ov;
      ov.x = f2bf(accv[mf][0]); ov.y = f2bf(accv[mf][1]);
      ov.z = f2bf(accv[mf][2]); ov.w = f2bf(accv[mf][3]);
      *(ushort4*)&vt[mf*16 + lr][w*16 + lc*4] = ov;
      ushort4 og;
      og.x = f2bf(1.0f/(1.0f + __expf(-accg[mf][0])));
      og.y = f2bf(1.0f/(1.0f + __expf(-accg[mf][1])));
      og.z = f2bf(1.0f/(1.0f + __expf(-accg[mf][2])));
      og.w = f2bf(1.0f/(1.0f + __expf(-accg[mf][3])));
      *(ushort4*)&gt[w*16 + lr][mf*16 + lc*4] = og;
    }
    __syncthreads();
    #pragma unroll
    for (int it = 0; it < 2; ++it){
      int fl = it*256 + tid;
      int j = fl >> 3, chunk = fl & 7;
      uint4 val = *(const uint4*)&vt[j][chunk*8];
      *(uint4*)(v + ((size_t)(j >> 3)*4096 + (size_t)b*8 + (j & 7))*NRES + k0 + chunk*8) = val;
    }
    #pragma unroll
    for (int it = 0; it < 2; ++it){
      int fl = it*256 + tid;
      int k = fl >> 3, chunk = fl & 7;
      uint4 val = *(const uint4*)&gt[k][chunk*8];
      *(uint4*)(gate + ((size_t)b*NRES + k0 + k)*MSAC + chunk*8) = val;
    }
  }
}

// ------- K4: per-head GEMM  Y3[h][bx][q][cl] = weights[h] @ v[h] -------
// 2-phase double-buffered pipeline, BK=32, single barrier per K-step.
__global__ __launch_bounds__(256) void k_wavg(
    const unsigned short* __restrict__ V, const unsigned short* __restrict__ W,
    unsigned short* __restrict__ Y)
{
  __shared__ unsigned char smem[32768];

  const int flat = blockIdx.x;
  const int nid  = (flat & 7) * 192 + (flat >> 3);   // XCD chunk of 192 = 1 head
  const int m    = nid % 192;
  const int by   = m % 6;              // fastest: A-tile reuse across 6 blocks
  const int bx   = m / 6;
  const int h    = nid / 192;

  const int tid = threadIdx.x, wid = tid >> 6, lane = tid & 63;
  const int wm = wid & 1, wn = wid >> 1;
  const unsigned short* Ag = V + (size_t)h*4096*768 + (size_t)bx*128*768;
  const unsigned short* Bg = W + (size_t)h*768*768 + (size_t)by*128*768;

  f32x4 acc[4][4];
  #pragma unroll
  for (int i=0;i<4;++i){
    #pragma unroll
    for (int jj=0;jj<4;++jj) acc[i][jj] = 0.f;
  }

  #define STAGE_K(bufsel, kt) { \
    unsigned char* Ab = smem + (bufsel)*16384; \
    unsigned char* Bb = Ab + 8192; \
    _Pragma("unroll") \
    for (int r = 0; r < 2; ++r){ \
      int cid = tid + r*256; \
      int rw = cid >> 2, ch = cid & 3; \
      int sc = ch ^ ((rw >> 1) & 3); \
      glds16(Ag + (size_t)rw*768 + (kt)*32 + sc*8, Ab + cid*16 - lane*16); \
      glds16(Bg + (size_t)rw*768 + (kt)*32 + sc*8, Bb + cid*16 - lane*16); \
    } }

  STAGE_K(0, 0);
  __syncthreads();
  const int c0 = lane >> 4;            // k-chunk selector
  for (int kt = 0; kt < 24; ++kt){
    if (kt < 23) STAGE_K((kt+1)&1, kt+1);     // prefetch overlaps compute below
    unsigned char* Ab = smem + (kt&1)*16384;
    unsigned char* Bb = Ab + 8192;
    short8_t af[4], bf[4];
    #pragma unroll
    for (int mf = 0; mf < 4; ++mf){
      int row = wm*64 + mf*16 + (lane & 15);
      int off = row*64 + ((c0 ^ ((row>>1)&3)) << 4);
      af[mf] = *(const short8_t*)(Ab + off);
    }
    #pragma unroll
    for (int nf = 0; nf < 4; ++nf){
      int row = wn*64 + nf*16 + (lane & 15);
      int off = row*64 + ((c0 ^ ((row>>1)&3)) << 4);
      bf[nf] = *(const short8_t*)(Bb + off);
    }
    #pragma unroll
    for (int mf = 0; mf < 4; ++mf){
      #pragma unroll
      for (int nf = 0; nf < 4; ++nf)
        acc[mf][nf] = __builtin_amdgcn_mfma_f32_16x16x32_bf16(af[mf], bf[nf], acc[mf][nf], 0, 0, 0);
    }
    __syncthreads();   // single drain per step
  }
  #undef STAGE_K

  // ---- epilogue: D -> swizzled LDS (aliases bufs) -> contiguous 32 KB store ----
  unsigned char* Ds = smem;              // 32 KB: [q_local 128][bc_local 128] bf16
  #pragma unroll
  for (int mf = 0; mf < 4; ++mf){
    int bc = wm*64 + mf*16 + ((lane >> 4) << 2);
    #pragma unroll
    for (int nf = 0; nf < 4; ++nf){
      int q = wn*64 + nf*16 + (lane & 15);
      f32x4 a = acc[mf][nf];
      ushort4 o;
      o.x = f2bf(a[0]); o.y = f2bf(a[1]); o.z = f2bf(a[2]); o.w = f2bf(a[3]);
      int off = q*256 + bc*2; off ^= (q & 7) << 4;
      *(ushort4*)(Ds + off) = o;
    }
  }
  __syncthreads();
  unsigned short* Yb = Y + ((size_t)(h*32 + bx)*768 + by*128)*128;
  #pragma unroll
  for (int it = 0; it < 8; ++it){
    int fl = it*256 + tid;
    int q = fl >> 4, chunk = fl & 15;
    int off = q*256 + chunk*16; off ^= (q & 7) << 4;
    uint4 val = *(const uint4*)(Ds + off);
    *(uint4*)(Yb + (size_t)fl*8) = val;
  }
}

// ------- K5: out[b][q][:] = (y*gate) @ wout^T via MFMA (hi/lo split) -------
// XCD-aware mapping: each XCD owns a contiguous 64-b slab so the 4 b-values
// sharing each 64B Y-line are consumed from ONE L2 (kills 4x Y over-fetch).
__global__ __launch_bounds__(256) void k_final(
    const unsigned short* __restrict__ Y, const unsigned short* __restrict__ gate,
    const unsigned short* __restrict__ WoH, const unsigned short* __restrict__ WoL,
    float* __restrict__ out)
{
  const int p = blockIdx.x;
  const int r = p & 7, t = p >> 3;
  const int b  = r*64 + (t & 63);
  const int q0 = (t >> 6) * 64;
  const int tid = threadIdx.x, w = tid >> 6, lane = tid & 63;
  const int lr = lane & 15, lc = lane >> 4;

  short8_t bh[4][2], bl[4][2];
  #pragma unroll
  for (int nf = 0; nf < 4; ++nf){
    #pragma unroll
    for (int s = 0; s < 2; ++s){
      bh[nf][s] = *(const short8_t*)(WoH + (nf*16 + lr)*64 + s*32 + lc*8);
      bl[nf][s] = *(const short8_t*)(WoL + (nf*16 + lr)*64 + s*32 + lc*8);
    }
  }

  const int q = q0 + w*16 + lr;
  short8_t ah[2], al[2];
  #pragma unroll
  for (int s = 0; s < 2; ++s){
    const int hh = s*4 + lc;          // head = i>>3
    short8_t y8 = *(const short8_t*)(Y + ((size_t)(hh*32 + (b >> 4))*768 + q)*128 + (b & 15)*8);
    short8_t g8 = *(const short8_t*)(gate + ((size_t)b*NRES + q)*MSAC + s*32 + lc*8);
    #pragma unroll
    for (int e = 0; e < 8; ++e){
      float pp = bf2f((unsigned short)y8[e]) * bf2f((unsigned short)g8[e]);
      unsigned short hi = f2bf(pp);
      ah[s][e] = (short)hi;
      al[s][e] = (short)f2bf(pp - bf2f(hi));
    }
  }

  f32x4 acc[4];
  #pragma unroll
  for (int nf = 0; nf < 4; ++nf) acc[nf] = 0.f;
  #pragma unroll
  for (int nf = 0; nf < 4; ++nf){
    #pragma unroll
    for (int s = 0; s < 2; ++s){
      acc[nf] = __builtin_amdgcn_mfma_f32_16x16x32_bf16(ah[s], bh[nf][s], acc[nf], 0, 0, 0);
      acc[nf] = __builtin_amdgcn_mfma_f32_16x16x32_bf16(al[s], bh[nf][s], acc[nf], 0, 0, 0);
      acc[nf] = __builtin_amdgcn_mfma_f32_16x16x32_bf16(ah[s], bl[nf][s], acc[nf], 0, 0, 0);
    }
  }

  #pragma unroll
  for (int nf = 0; nf < 4; ++nf){
    #pragma unroll
    for (int e = 0; e < 4; ++e){
      int qq = q0 + w*16 + lc*4 + e;
      out[((size_t)b*NRES + qq)*MSAC + nf*16 + lr] = acc[nf][e];
    }
  }
}

extern "C" void kernel_launch(void* const* d_in, const int* in_sizes, int n_in,
                              void* d_out, int out_size, void* d_ws, size_t ws_size,
                              hipStream_t stream) {
  (void)in_sizes; (void)n_in; (void)out_size; (void)ws_size;
  const float* act    = (const float*)d_in[0];
  const float* mask   = (const float*)d_in[1];
  const float* pair   = (const float*)d_in[2];
  const float* ascale = (const float*)d_in[3];
  const float* abias  = (const float*)d_in[4];
  const float* pscale = (const float*)d_in[5];
  const float* pbias  = (const float*)d_in[6];
  const float* wl     = (const float*)d_in[7];
  const float* vproj  = (const float*)d_in[8];
  const float* wgate  = (const float*)d_in[9];
  const float* wout   = (const float*)d_in[10];
  float* out = (float*)d_out;

  char* ws = (char*)d_ws;
  float*          mbias   = (float*)(ws);                                   // 3 KB
  unsigned short* WvT     = (unsigned short*)(ws + 4096);                   // 8 KB
  unsigned short* WgT     = (unsigned short*)(ws + 12288);                  // 8 KB
  unsigned short* WoH     = (unsigned short*)(ws + 20480);                  // 8 KB
  unsigned short* WoL     = (unsigned short*)(ws + 28672);                  // 8 KB
  unsigned short* weights = (unsigned short*)(ws + 36864);                  // 9.4 MB  [h][q][k]
  unsigned short* v       = (unsigned short*)(ws + 36864 + 9437184);        // 50.3 MB [h][bc][k]
  unsigned short* gate    = (unsigned short*)(ws + 36864 + 9437184 + 50331648);       // 50.3 MB [b][k][64]
  unsigned short* y       = (unsigned short*)(ws + 36864 + 9437184 + 2*50331648ull);  // 50.3 MB [h][bx][q][cl]

  k_prep2<<<dim3(28), dim3(256), 0, stream>>>(mask, vproj, wgate, wout,
                                              mbias, WvT, WgT, WoH, WoL);
  k_pairact<<<dim3(6912), dim3(256), 0, stream>>>(pair, pscale, pbias, wl, mbias, weights,
                                                  act, ascale, abias, WvT, WgT, v, gate);
  k_wavg<<<dim3(1536), dim3(256), 0, stream>>>(v, weights, y);
  k_final<<<dim3(6144), dim3(256), 0, stream>>>(y, gate, WoH, WoL, out);
}

// Round 9
// 307.670 us; speedup vs baseline: 2.6442x; 1.0767x over previous
//
#include <hip/hip_runtime.h>
#include <hip/hip_bf16.h>

#define NSEQ 512
#define NRES 768
#define MSAC 64
#define PAIRC 128
#define NHEAD 8

typedef __attribute__((ext_vector_type(8))) short short8_t;
typedef __attribute__((ext_vector_type(4))) float f32x4;

__device__ __forceinline__ float bf2f(unsigned short u){
  return __uint_as_float(((unsigned int)u) << 16);
}
__device__ __forceinline__ unsigned short f2bf(float f){
  unsigned int x = __float_as_uint(f);
  x += 0x7fffu + ((x >> 16) & 1u);   // RTNE
  return (unsigned short)(x >> 16);
}
// async global->LDS, 16B per lane; lds base must be wave-uniform (lane*16 implicit)
__device__ __forceinline__ void glds16(const void* g, void* l){
  __builtin_amdgcn_global_load_lds(
      (const __attribute__((address_space(1))) unsigned int*)g,
      (__attribute__((address_space(3))) unsigned int*)l, 16, 0, 0);
}

// -------- K0: mask max + weight prep (WvT/WgT/WoH/WoL + WST/AB for pair) --------
// WST[16][128] bf16: rows 0-7 = hi(pscale*wl), rows 8-15 = lo residual.
// AB[0..7] = sum_c pscale*wl (f32), AB[8..15] = sum_c pbias*wl (f32).
__global__ __launch_bounds__(256) void k_prep2(
    const float* __restrict__ mask, const float* __restrict__ vproj,
    const float* __restrict__ wgate, const float* __restrict__ wout,
    const float* __restrict__ pscale, const float* __restrict__ pbias,
    const float* __restrict__ wl,
    float* __restrict__ bias, unsigned short* __restrict__ WvT,
    unsigned short* __restrict__ WgT, unsigned short* __restrict__ WoH,
    unsigned short* __restrict__ WoL, unsigned short* __restrict__ WST,
    float* __restrict__ AB)
{
  const int bid = blockIdx.x, tid = threadIdx.x;
  if (bid < 12){
    __shared__ float red[4][64];
    const int kk = bid*64 + (tid & 63);
    const int bs = tid >> 6;
    float m = -1e30f;
    for (int b = bs; b < NSEQ; b += 4) m = fmaxf(m, mask[(size_t)b*NRES + kk]);
    red[bs][tid & 63] = m;
    __syncthreads();
    if (tid < 64){
      float mm = fmaxf(fmaxf(red[0][tid], red[1][tid]),
                       fmaxf(red[2][tid], red[3][tid]));
      bias[bid*64 + tid] = 1e9f * (bf2f(f2bf(mm)) - 1.0f);  // ref casts max to bf16
    }
  } else if (bid < 28){
    const int t = (bid - 12)*256 + tid;   // 4096 total
    const int j = t >> 6, i = t & 63;
    WvT[t] = f2bf(vproj[i*64 + j]);
    WgT[t] = f2bf(wgate[t]);
    float wv = wout[t];
    unsigned short hh = f2bf(wv);
    WoH[t] = hh;
    WoL[t] = f2bf(wv - bf2f(hh));
  } else {
    // WST hi/lo
    #pragma unroll
    for (int i = 0; i < 4; ++i){
      int t = i*256 + tid;              // 1024 entries
      int h = t >> 7, c = t & 127;
      float w = pscale[c] * wl[h*PAIRC + c];
      unsigned short hh = f2bf(w);
      WST[h*PAIRC + c] = hh;
      WST[(h + 8)*PAIRC + c] = f2bf(w - bf2f(hh));
    }
    // AB scalars: tid<256, h = tid>>5, cc = tid&31
    const int h = tid >> 5, cc = tid & 31;
    float pa = 0.f, pb = 0.f;
    for (int c = cc; c < PAIRC; c += 32){
      float w = wl[h*PAIRC + c];
      pa += pscale[c]*w;  pb += pbias[c]*w;
    }
    #pragma unroll
    for (int m = 1; m < 32; m <<= 1){
      pa += __shfl_xor(pa, m, 64);
      pb += __shfl_xor(pb, m, 64);
    }
    if (cc == 0){ AB[h] = pa; AB[8 + h] = pb; }
  }
}

// ------- K1: merged pair-path (MFMA logits) + act-path -------
// bid < 768: pair LN+logits via algebraic rewrite + MFMA, softmax -> weights[h][q][k]
// bid >= 768: act LN + v/gate via register-direct MFMA
__global__ __launch_bounds__(256) void k_pairact(
    const float* __restrict__ pair, const unsigned short* __restrict__ WST,
    const float* __restrict__ AB, const float* __restrict__ mbias,
    unsigned short* __restrict__ weights,
    const float* __restrict__ act, const float* __restrict__ ascale,
    const float* __restrict__ abias, const unsigned short* __restrict__ WvT,
    const unsigned short* __restrict__ WgT, unsigned short* __restrict__ v,
    unsigned short* __restrict__ gate)
{
  __shared__ __align__(16) unsigned char sm[24576];   // union: lg[8][768] f32 | vt+gt
  const int bid = blockIdx.x;
  const int tid = threadIdx.x;

  if (bid < 768){
    // =================== pair role ===================
    float (*lg)[NRES] = (float (*)[NRES])sm;   // 24 KB
    const int q = bid;
    const int wv = tid >> 6, lane = tid & 63;
    const int lr = lane & 15, lcq = lane >> 4;

    // stacked weight fragments [wh;wl], loaded once, reused for all tiles
    short8_t wfrag[4];
    #pragma unroll
    for (int s = 0; s < 4; ++s)
      wfrag[s] = *(const short8_t*)(WST + lr*PAIRC + lcq*8 + s*32);

    // per-lane head constants for epilogue (lanes 0-31: h = hb + r)
    const int hb = (lcq & 1) * 4;
    float A4[4], B4[4];
    #pragma unroll
    for (int r = 0; r < 4; ++r){ A4[r] = AB[hb + r]; B4[r] = AB[8 + hb + r]; }

    for (int tile = wv; tile < 48; tile += 4){
      const int k0 = tile * 16;
      const float* base = pair + ((size_t)q*NRES + k0 + lr)*PAIRC + lcq*8;
      f32x4 a1 = 0.f, a2 = 0.f;
      float s = 0.f, ss = 0.f;
      #pragma unroll
      for (int st = 0; st < 4; ++st){
        float4 u0 = *(const float4*)(base + st*32);
        float4 u1 = *(const float4*)(base + st*32 + 4);
        float xv[8] = {u0.x,u0.y,u0.z,u0.w,u1.x,u1.y,u1.z,u1.w};
        short8_t xh, xl;
        #pragma unroll
        for (int e = 0; e < 8; ++e){
          s += xv[e]; ss += xv[e]*xv[e];
          unsigned short hi = f2bf(xv[e]);
          xh[e] = (short)hi;
          xl[e] = (short)f2bf(xv[e] - bf2f(hi));
        }
        a1 = __builtin_amdgcn_mfma_f32_16x16x32_bf16(wfrag[st], xh, a1, 0, 0, 0);
        a2 = __builtin_amdgcn_mfma_f32_16x16x32_bf16(wfrag[st], xl, a2, 0, 0, 0);
      }
      // s/ss over the 4 lanes sharing k (l^16, l^32)
      s  += __shfl_xor(s, 16, 64);  ss += __shfl_xor(ss, 16, 64);
      s  += __shfl_xor(s, 32, 64);  ss += __shfl_xor(ss, 32, 64);
      const float mu  = s * (1.f/128.f);
      const float var = ss * (1.f/128.f) - mu*mu;
      const float rsq = rsqrtf(var + 1e-5f);
      // d[h][k] = wh@xh + wl@xh (rows 8-15, via lane^32) + wh@xl
      float d[4];
      #pragma unroll
      for (int r = 0; r < 4; ++r)
        d[r] = a1[r] + __shfl_xor(a1[r], 32, 64) + a2[r];
      if (lane < 32){
        const int k = k0 + lr;
        #pragma unroll
        for (int r = 0; r < 4; ++r)
          lg[hb + r][k] = rsq * (d[r] - mu * A4[r]) + B4[r];
      }
    }
    __syncthreads();
    // softmax: wave wv handles heads wv and wv+4
    #pragma unroll
    for (int hh = 0; hh < 2; ++hh){
      int h = wv + hh*4;
      float mx = -1e30f;
      for (int kk = lane; kk < NRES; kk += 64) mx = fmaxf(mx, lg[h][kk] + mbias[kk]);
      #pragma unroll
      for (int m = 1; m < 64; m <<= 1) mx = fmaxf(mx, __shfl_xor(mx, m, 64));
      float sum = 0.f;
      for (int kk = lane; kk < NRES; kk += 64){
        float e = __expf(lg[h][kk] + mbias[kk] - mx);
        lg[h][kk] = e; sum += e;
      }
      #pragma unroll
      for (int m = 1; m < 64; m <<= 1) sum += __shfl_xor(sum, m, 64);
      float inv = 1.0f / sum;
      unsigned short* wrow = weights + ((size_t)h * NRES + q) * NRES;
      for (int kk = lane; kk < NRES; kk += 64) wrow[kk] = f2bf(lg[h][kk] * inv);
    }
  } else {
    // =================== act role ===================
    unsigned short (*vt)[72] = (unsigned short (*)[72])sm;            // 9216 B
    unsigned short (*gt)[72] = (unsigned short (*)[72])(sm + 9216);   // 9216 B
    const int abid = bid - 768;
    const int b  = abid / 12;
    const int k0 = (abid % 12) * 64;
    const int w = tid >> 6, lane = tid & 63;
    const int lr = lane & 15;
    const int lc = lane >> 4;
    const int row = k0 + w*16 + lr;

    const float* arow = act + ((size_t)b*NRES + row)*MSAC;
    float x[2][8];
    #pragma unroll
    for (int s = 0; s < 2; ++s){
      float4 t0 = *(const float4*)(arow + s*32 + lc*8);
      float4 t1 = *(const float4*)(arow + s*32 + lc*8 + 4);
      x[s][0]=t0.x; x[s][1]=t0.y; x[s][2]=t0.z; x[s][3]=t0.w;
      x[s][4]=t1.x; x[s][5]=t1.y; x[s][6]=t1.z; x[s][7]=t1.w;
    }
    float ps = 0.f, pss = 0.f;
    #pragma unroll
    for (int s = 0; s < 2; ++s)
      #pragma unroll
      for (int e = 0; e < 8; ++e){ ps += x[s][e]; pss += x[s][e]*x[s][e]; }
    ps  += __shfl_xor(ps, 16, 64);  pss += __shfl_xor(pss, 16, 64);
    ps  += __shfl_xor(ps, 32, 64);  pss += __shfl_xor(pss, 32, 64);
    const float mu  = ps * (1.f/64.f);
    const float var = pss * (1.f/64.f) - mu*mu;
    const float rs  = rsqrtf(var + 1e-5f);

    short8_t a[2];
    #pragma unroll
    for (int s = 0; s < 2; ++s){
      float4 s0 = *(const float4*)(ascale + s*32 + lc*8);
      float4 s1 = *(const float4*)(ascale + s*32 + lc*8 + 4);
      float4 b0 = *(const float4*)(abias  + s*32 + lc*8);
      float4 b1 = *(const float4*)(abias  + s*32 + lc*8 + 4);
      const float sc[8] = {s0.x,s0.y,s0.z,s0.w,s1.x,s1.y,s1.z,s1.w};
      const float bs[8] = {b0.x,b0.y,b0.z,b0.w,b1.x,b1.y,b1.z,b1.w};
      #pragma unroll
      for (int e = 0; e < 8; ++e)
        a[s][e] = (short)f2bf((x[s][e] - mu)*rs*sc[e] + bs[e]);
    }

    short8_t bv[4][2], bg[4][2];
    #pragma unroll
    for (int mf = 0; mf < 4; ++mf){
      #pragma unroll
      for (int s = 0; s < 2; ++s){
        bv[mf][s] = *(const short8_t*)(WvT + (mf*16 + lr)*64 + s*32 + lc*8);
        bg[mf][s] = *(const short8_t*)(WgT + (mf*16 + lr)*64 + s*32 + lc*8);
      }
    }

    f32x4 accv[4], accg[4];
    #pragma unroll
    for (int mf = 0; mf < 4; ++mf){ accv[mf] = 0.f; accg[mf] = 0.f; }
    #pragma unroll
    for (int mf = 0; mf < 4; ++mf){
      #pragma unroll
      for (int s = 0; s < 2; ++s){
        accv[mf] = __builtin_amdgcn_mfma_f32_16x16x32_bf16(a[s], bv[mf][s], accv[mf], 0, 0, 0);
        accg[mf] = __builtin_amdgcn_mfma_f32_16x16x32_bf16(bg[mf][s], a[s], accg[mf], 0, 0, 0);
      }
    }

    #pragma unroll
    for (int mf = 0; mf < 4; ++mf){
      ushort4 ov;
      ov.x = f2bf(accv[mf][0]); ov.y = f2bf(accv[mf][1]);
      ov.z = f2bf(accv[mf][2]); ov.w = f2bf(accv[mf][3]);
      *(ushort4*)&vt[mf*16 + lr][w*16 + lc*4] = ov;
      ushort4 og;
      og.x = f2bf(1.0f/(1.0f + __expf(-accg[mf][0])));
      og.y = f2bf(1.0f/(1.0f + __expf(-accg[mf][1])));
      og.z = f2bf(1.0f/(1.0f + __expf(-accg[mf][2])));
      og.w = f2bf(1.0f/(1.0f + __expf(-accg[mf][3])));
      *(ushort4*)&gt[w*16 + lr][mf*16 + lc*4] = og;
    }
    __syncthreads();
    #pragma unroll
    for (int it = 0; it < 2; ++it){
      int fl = it*256 + tid;
      int j = fl >> 3, chunk = fl & 7;
      uint4 val = *(const uint4*)&vt[j][chunk*8];
      *(uint4*)(v + ((size_t)(j >> 3)*4096 + (size_t)b*8 + (j & 7))*NRES + k0 + chunk*8) = val;
    }
    #pragma unroll
    for (int it = 0; it < 2; ++it){
      int fl = it*256 + tid;
      int k = fl >> 3, chunk = fl & 7;
      uint4 val = *(const uint4*)&gt[k][chunk*8];
      *(uint4*)(gate + ((size_t)b*NRES + k0 + k)*MSAC + chunk*8) = val;
    }
  }
}

// ------- K4: per-head GEMM  Y3[h][bx][q][cl] = weights[h] @ v[h] -------
// 2-phase double-buffered pipeline, BK=32, single barrier per K-step.
__global__ __launch_bounds__(256) void k_wavg(
    const unsigned short* __restrict__ V, const unsigned short* __restrict__ W,
    unsigned short* __restrict__ Y)
{
  __shared__ unsigned char smem[32768];

  const int flat = blockIdx.x;
  const int nid  = (flat & 7) * 192 + (flat >> 3);   // XCD chunk of 192 = 1 head
  const int m    = nid % 192;
  const int by   = m % 6;              // fastest: A-tile reuse across 6 blocks
  const int bx   = m / 6;
  const int h    = nid / 192;

  const int tid = threadIdx.x, wid = tid >> 6, lane = tid & 63;
  const int wm = wid & 1, wn = wid >> 1;
  const unsigned short* Ag = V + (size_t)h*4096*768 + (size_t)bx*128*768;
  const unsigned short* Bg = W + (size_t)h*768*768 + (size_t)by*128*768;

  f32x4 acc[4][4];
  #pragma unroll
  for (int i=0;i<4;++i){
    #pragma unroll
    for (int jj=0;jj<4;++jj) acc[i][jj] = 0.f;
  }

  #define STAGE_K(bufsel, kt) { \
    unsigned char* Ab = smem + (bufsel)*16384; \
    unsigned char* Bb = Ab + 8192; \
    _Pragma("unroll") \
    for (int r = 0; r < 2; ++r){ \
      int cid = tid + r*256; \
      int rw = cid >> 2, ch = cid & 3; \
      int sc = ch ^ ((rw >> 1) & 3); \
      glds16(Ag + (size_t)rw*768 + (kt)*32 + sc*8, Ab + cid*16 - lane*16); \
      glds16(Bg + (size_t)rw*768 + (kt)*32 + sc*8, Bb + cid*16 - lane*16); \
    } }

  STAGE_K(0, 0);
  __syncthreads();
  const int c0 = lane >> 4;            // k-chunk selector
  for (int kt = 0; kt < 24; ++kt){
    if (kt < 23) STAGE_K((kt+1)&1, kt+1);     // prefetch overlaps compute below
    unsigned char* Ab = smem + (kt&1)*16384;
    unsigned char* Bb = Ab + 8192;
    short8_t af[4], bf[4];
    #pragma unroll
    for (int mf = 0; mf < 4; ++mf){
      int row = wm*64 + mf*16 + (lane & 15);
      int off = row*64 + ((c0 ^ ((row>>1)&3)) << 4);
      af[mf] = *(const short8_t*)(Ab + off);
    }
    #pragma unroll
    for (int nf = 0; nf < 4; ++nf){
      int row = wn*64 + nf*16 + (lane & 15);
      int off = row*64 + ((c0 ^ ((row>>1)&3)) << 4);
      bf[nf] = *(const short8_t*)(Bb + off);
    }
    #pragma unroll
    for (int mf = 0; mf < 4; ++mf){
      #pragma unroll
      for (int nf = 0; nf < 4; ++nf)
        acc[mf][nf] = __builtin_amdgcn_mfma_f32_16x16x32_bf16(af[mf], bf[nf], acc[mf][nf], 0, 0, 0);
    }
    __syncthreads();   // single drain per step
  }
  #undef STAGE_K

  // ---- epilogue: D -> swizzled LDS (aliases bufs) -> contiguous 32 KB store ----
  unsigned char* Ds = smem;              // 32 KB: [q_local 128][bc_local 128] bf16
  #pragma unroll
  for (int mf = 0; mf < 4; ++mf){
    int bc = wm*64 + mf*16 + ((lane >> 4) << 2);
    #pragma unroll
    for (int nf = 0; nf < 4; ++nf){
      int q = wn*64 + nf*16 + (lane & 15);
      f32x4 a = acc[mf][nf];
      ushort4 o;
      o.x = f2bf(a[0]); o.y = f2bf(a[1]); o.z = f2bf(a[2]); o.w = f2bf(a[3]);
      int off = q*256 + bc*2; off ^= (q & 7) << 4;
      *(ushort4*)(Ds + off) = o;
    }
  }
  __syncthreads();
  unsigned short* Yb = Y + ((size_t)(h*32 + bx)*768 + by*128)*128;
  #pragma unroll
  for (int it = 0; it < 8; ++it){
    int fl = it*256 + tid;
    int q = fl >> 4, chunk = fl & 15;
    int off = q*256 + chunk*16; off ^= (q & 7) << 4;
    uint4 val = *(const uint4*)(Ds + off);
    *(uint4*)(Yb + (size_t)fl*8) = val;
  }
}

// ------- K5: out[b][q][:] = (y*gate) @ wout^T via MFMA (hi/lo split) -------
// XCD-aware mapping: each XCD owns a contiguous 64-b slab so the 4 b-values
// sharing each 64B Y-line are consumed from ONE L2.
__global__ __launch_bounds__(256) void k_final(
    const unsigned short* __restrict__ Y, const unsigned short* __restrict__ gate,
    const unsigned short* __restrict__ WoH, const unsigned short* __restrict__ WoL,
    float* __restrict__ out)
{
  const int p = blockIdx.x;
  const int r = p & 7, t = p >> 3;
  const int b  = r*64 + (t & 63);
  const int q0 = (t >> 6) * 64;
  const int tid = threadIdx.x, w = tid >> 6, lane = tid & 63;
  const int lr = lane & 15, lc = lane >> 4;

  short8_t bh[4][2], bl[4][2];
  #pragma unroll
  for (int nf = 0; nf < 4; ++nf){
    #pragma unroll
    for (int s = 0; s < 2; ++s){
      bh[nf][s] = *(const short8_t*)(WoH + (nf*16 + lr)*64 + s*32 + lc*8);
      bl[nf][s] = *(const short8_t*)(WoL + (nf*16 + lr)*64 + s*32 + lc*8);
    }
  }

  const int q = q0 + w*16 + lr;
  short8_t ah[2], al[2];
  #pragma unroll
  for (int s = 0; s < 2; ++s){
    const int hh = s*4 + lc;          // head = i>>3
    short8_t y8 = *(const short8_t*)(Y + ((size_t)(hh*32 + (b >> 4))*768 + q)*128 + (b & 15)*8);
    short8_t g8 = *(const short8_t*)(gate + ((size_t)b*NRES + q)*MSAC + s*32 + lc*8);
    #pragma unroll
    for (int e = 0; e < 8; ++e){
      float pp = bf2f((unsigned short)y8[e]) * bf2f((unsigned short)g8[e]);
      unsigned short hi = f2bf(pp);
      ah[s][e] = (short)hi;
      al[s][e] = (short)f2bf(pp - bf2f(hi));
    }
  }

  f32x4 acc[4];
  #pragma unroll
  for (int nf = 0; nf < 4; ++nf) acc[nf] = 0.f;
  #pragma unroll
  for (int nf = 0; nf < 4; ++nf){
    #pragma unroll
    for (int s = 0; s < 2; ++s){
      acc[nf] = __builtin_amdgcn_mfma_f32_16x16x32_bf16(ah[s], bh[nf][s], acc[nf], 0, 0, 0);
      acc[nf] = __builtin_amdgcn_mfma_f32_16x16x32_bf16(al[s], bh[nf][s], acc[nf], 0, 0, 0);
      acc[nf] = __builtin_amdgcn_mfma_f32_16x16x32_bf16(ah[s], bl[nf][s], acc[nf], 0, 0, 0);
    }
  }

  #pragma unroll
  for (int nf = 0; nf < 4; ++nf){
    #pragma unroll
    for (int e = 0; e < 4; ++e){
      int qq = q0 + w*16 + lc*4 + e;
      out[((size_t)b*NRES + qq)*MSAC + nf*16 + lr] = acc[nf][e];
    }
  }
}

extern "C" void kernel_launch(void* const* d_in, const int* in_sizes, int n_in,
                              void* d_out, int out_size, void* d_ws, size_t ws_size,
                              hipStream_t stream) {
  (void)in_sizes; (void)n_in; (void)out_size; (void)ws_size;
  const float* act    = (const float*)d_in[0];
  const float* mask   = (const float*)d_in[1];
  const float* pair   = (const float*)d_in[2];
  const float* ascale = (const float*)d_in[3];
  const float* abias  = (const float*)d_in[4];
  const float* pscale = (const float*)d_in[5];
  const float* pbias  = (const float*)d_in[6];
  const float* wl     = (const float*)d_in[7];
  const float* vproj  = (const float*)d_in[8];
  const float* wgate  = (const float*)d_in[9];
  const float* wout   = (const float*)d_in[10];
  float* out = (float*)d_out;

  char* ws = (char*)d_ws;
  float*          mbias   = (float*)(ws);                                   // 3 KB
  unsigned short* WvT     = (unsigned short*)(ws + 4096);                   // 8 KB
  unsigned short* WgT     = (unsigned short*)(ws + 12288);                  // 8 KB
  unsigned short* WoH     = (unsigned short*)(ws + 20480);                  // 8 KB
  unsigned short* WoL     = (unsigned short*)(ws + 28672);                  // 8 KB
  unsigned short* WST     = (unsigned short*)(ws + 36864);                  // 4 KB
  float*          AB      = (float*)(ws + 40960);                           // 64 B
  unsigned short* weights = (unsigned short*)(ws + 45056);                  // 9.4 MB  [h][q][k]
  unsigned short* v       = (unsigned short*)(ws + 45056 + 9437184);        // 50.3 MB [h][bc][k]
  unsigned short* gate    = (unsigned short*)(ws + 45056 + 9437184 + 50331648);       // 50.3 MB [b][k][64]
  unsigned short* y       = (unsigned short*)(ws + 45056 + 9437184 + 2*50331648ull);  // 50.3 MB [h][bx][q][cl]

  k_prep2<<<dim3(29), dim3(256), 0, stream>>>(mask, vproj, wgate, wout,
                                              pscale, pbias, wl,
                                              mbias, WvT, WgT, WoH, WoL, WST, AB);
  k_pairact<<<dim3(6912), dim3(256), 0, stream>>>(pair, WST, AB, mbias, weights,
                                                  act, ascale, abias, WvT, WgT, v, gate);
  k_wavg<<<dim3(1536), dim3(256), 0, stream>>>(v, weights, y);
  k_final<<<dim3(6144), dim3(256), 0, stream>>>(y, gate, WoH, WoL, out);
}